// Round 10
// baseline (356.748 us; speedup 1.0000x reference)
//
#include <hip/hip_runtime.h>

typedef __attribute__((ext_vector_type(8))) short short8;   // 8 bf16
typedef __attribute__((ext_vector_type(4))) float f32x4;

__device__ inline ushort f2bf(float f) {
    union { float f; unsigned u; } v{f};
    unsigned r = v.u + 0x7FFF + ((v.u >> 16) & 1);
    return (ushort)(r >> 16);
}

// CK-style addrspace casts (low 32 bits of a flat LDS address == LDS offset).
__device__ inline void gload_lds16(const void* g, void* l) {
    __builtin_amdgcn_global_load_lds(
        (const __attribute__((address_space(1))) unsigned int*)(uintptr_t)g,
        (__attribute__((address_space(3))) unsigned int*)(uintptr_t)l,
        16, 0, 0);
}

// ---------------------------------------------------------------------------
// sen1/sen2 f32 [8192][300] -> Senb bf16 [16384][320] (zero-padded) and
// Xcat bf16 [16384][608]: cols 0..299 = sen, cols 600..607 = 0.
// ---------------------------------------------------------------------------
__global__ __launch_bounds__(256) void convert_inputs_kernel(
    const float* __restrict__ sen1, const float* __restrict__ sen2,
    ushort* __restrict__ Senb, ushort* __restrict__ Xcat)
{
    const int row = blockIdx.x * 8 + (threadIdx.x >> 5);
    const int c0 = threadIdx.x & 31;
    const float* src = (row < 8192) ? (sen1 + (size_t)row * 300)
                                    : (sen2 + (size_t)(row - 8192) * 300);
    ushort* sb = Senb + (size_t)row * 320;
    ushort* xc = Xcat + (size_t)row * 608;
    for (int c = c0; c < 320; c += 32) {
        ushort v = (c < 300) ? f2bf(src[c]) : (ushort)0;
        sb[c] = v;
        if (c < 300) xc[c] = v;
    }
    if (c0 < 8) xc[600 + c0] = 0;
}

// ---------------------------------------------------------------------------
// W [N][K] f32 -> Wb [224][KP] bf16 zero-padded; bias -> biasp [224] f32.
// ---------------------------------------------------------------------------
__global__ __launch_bounds__(256) void convert_weights_kernel(
    const float* __restrict__ W0, const float* __restrict__ b0,
    const float* __restrict__ W1, const float* __restrict__ b1,
    const float* __restrict__ W2, const float* __restrict__ b2,
    const float* __restrict__ W3, const float* __restrict__ b3,
    ushort* __restrict__ Wb0, float* __restrict__ bp0,
    ushort* __restrict__ Wb1, float* __restrict__ bp1,
    ushort* __restrict__ Wb2, float* __restrict__ bp2,
    ushort* __restrict__ Wb3, float* __restrict__ bp3)
{
    const int id = blockIdx.x;
    const int mat = id / 224, n = id % 224;
    const float* W; const float* b; ushort* Wb; float* bp; int N, K, KP;
    if (mat == 0)      { W = W0; b = b0; Wb = Wb0; bp = bp0; N = 200; K = 300; KP = 320; }
    else if (mat == 1) { W = W1; b = b1; Wb = Wb1; bp = bp1; N = 200; K = 200; KP = 224; }
    else if (mat == 2) { W = W2; b = b2; Wb = Wb2; bp = bp2; N = 200; K = 600; KP = 608; }
    else               { W = W3; b = b3; Wb = Wb3; bp = bp3; N = 200; K = 200; KP = 224; }
    for (int k = threadIdx.x; k < KP; k += 256)
        Wb[(size_t)n * KP + k] = (n < N && k < K) ? f2bf(W[(size_t)n * K + k]) : (ushort)0;
    if (threadIdx.x == 0) bp[n] = (n < N) ? b[n] : 0.f;
}

// ---------------------------------------------------------------------------
// sen f32 [8192][300] -> St bf16 [320][8192] transposed (pad rows zero).
// ---------------------------------------------------------------------------
__global__ __launch_bounds__(256) void transpose_bf16_kernel(
    const float* __restrict__ s1, const float* __restrict__ s2,
    ushort* __restrict__ St1, ushort* __restrict__ St2)
{
    const float* X = blockIdx.z ? s2 : s1;
    ushort* Xt = blockIdx.z ? St2 : St1;
    __shared__ float t[64][65];
    const int r0 = blockIdx.x * 64, c0 = blockIdx.y * 64;
    const int tc = threadIdx.x & 63, tr = threadIdx.x >> 6;
    for (int rr = tr; rr < 64; rr += 4) {
        int c = c0 + tc;
        t[rr][tc] = (c < 300) ? X[(size_t)(r0 + rr) * 300 + c] : 0.f;
    }
    __syncthreads();
    for (int rr = tr; rr < 64; rr += 4) {
        int oc = c0 + rr;
        if (oc < 320)
            Xt[(size_t)oc * 8192 + r0 + tc] = f2bf(t[tc][rr]);
    }
}

// ---------------------------------------------------------------------------
// Fused 2-layer MLP: Y = relu(relu(X@W1^T+b1)@W2^T+b2).
// X bf16 [M][KP1]; W1 [224][KP1]; W2 [224][224]; one wave, 16 rows/block.
// ---------------------------------------------------------------------------
__global__ __launch_bounds__(64) void mlp2_kernel(
    const ushort* __restrict__ X, int KP1,
    const ushort* __restrict__ W1, const float* __restrict__ b1,
    const ushort* __restrict__ W2, const float* __restrict__ b2,
    ushort* __restrict__ Ybf, float* __restrict__ Yf)
{
    const int r0 = blockIdx.x * 16;
    const int lane = threadIdx.x;
    const int lr = lane & 15, lg = lane >> 4;

    __shared__ __align__(16) ushort Y1[16][232];

    f32x4 a1[14];
#pragma unroll
    for (int t = 0; t < 14; ++t) a1[t] = f32x4{0.f, 0.f, 0.f, 0.f};

    const ushort* Xrow = X + (size_t)(r0 + lr) * KP1 + lg * 8;
    const ushort* W1r  = W1 + (size_t)lr * KP1 + lg * 8;
    for (int k0 = 0; k0 < KP1; k0 += 32) {
        short8 a = *(const short8*)(Xrow + k0);
#pragma unroll
        for (int t = 0; t < 14; ++t) {
            short8 bfr = *(const short8*)(W1r + (size_t)t * 16 * KP1 + k0);
            a1[t] = __builtin_amdgcn_mfma_f32_16x16x32_bf16(a, bfr, a1[t], 0, 0, 0);
        }
    }
#pragma unroll
    for (int t = 0; t < 14; ++t) {
        int col = t * 16 + lr;
        float bv = b1[col];
#pragma unroll
        for (int rr = 0; rr < 4; ++rr)
            Y1[lg * 4 + rr][col] = f2bf(fmaxf(a1[t][rr] + bv, 0.f));
    }
    __syncthreads();

    f32x4 a2[14];
#pragma unroll
    for (int t = 0; t < 14; ++t) a2[t] = f32x4{0.f, 0.f, 0.f, 0.f};
    const ushort* W2r = W2 + (size_t)lr * 224 + lg * 8;
    for (int k0 = 0; k0 < 224; k0 += 32) {
        short8 a = *(const short8*)&Y1[lr][lg * 8 + k0];
#pragma unroll
        for (int t = 0; t < 14; ++t) {
            short8 bfr = *(const short8*)(W2r + (size_t)t * 16 * 224 + k0);
            a2[t] = __builtin_amdgcn_mfma_f32_16x16x32_bf16(a, bfr, a2[t], 0, 0, 0);
        }
    }
#pragma unroll
    for (int t = 0; t < 14; ++t) {
        int col = t * 16 + lr;
        float bv = b2[col];
#pragma unroll
        for (int rr = 0; rr < 4; ++rr) {
            int row = r0 + lg * 4 + rr;
            float v = fmaxf(a2[t][rr] + bv, 0.f);
            if (Ybf) Ybf[(size_t)row * 224 + col] = f2bf(v);
            else if (col < 200) Yf[(size_t)row * 200 + col] = v;
        }
    }
}

// ---------------------------------------------------------------------------
// Flash attend, j-split, 2x2 E-wave-tiling, ONE barrier per iteration.
// 64 Q-rows x 4096 j per block, 4 waves, grid 512, 2 blocks/CU.
// Double-buffered Bl (global_load_lds staging issued at iter top, drained by
// this iter's single barrier -> full-E-phase latency cover) and Pl (PV(jb)
// reads Pl[cur] post-barrier while a fast wave's E(jb+64) writes Pl[cur^1]).
// Race audit: Bl[cur^1] last read in E(jb-64), pre-previous-barrier; Pl[cur]
// next written in E(jb+128), which is gated behind the barrier PV(jb)
// precedes. St loads issued early (st0 pre-E, st1 post-E) for L3 cover.
// ---------------------------------------------------------------------------
__global__ __launch_bounds__(256, 2) void attend_mfma_kernel(
    const ushort* __restrict__ FaFb, const ushort* __restrict__ St1,
    const ushort* __restrict__ St2, float* __restrict__ Pacc,
    float* __restrict__ Dpart)
{
    const int b = blockIdx.x;
    const int it  = b & 127;
    const int jh  = (b >> 7) & 1;
    const int dir = b >> 8;
    const ushort* A  = FaFb + (dir ? (size_t)8192 * 224 : 0);
    const ushort* B  = FaFb + (dir ? 0 : (size_t)8192 * 224);
    const ushort* St = dir ? St1 : St2;
    const int ib = it * 64;
    const int jo = jh * 4096;

    const int tid = threadIdx.x;
    const int w = tid >> 6;
    const int wi = w >> 1, wj = w & 1;
    const int lane = tid & 63;
    const int lr = lane & 15, lg = lane >> 4;

    // B tiles, MFMA-fragment layout: frag p = jgroup*7+kk, 1024 B each,
    // lane-linear 16 B (exactly global_load_lds's write pattern).
    __shared__ __align__(16) ushort Bl[2][28 * 512];   // 57,344 B
    __shared__ __align__(16) ushort Pl[2][64][76];     // 19,456 B
    __shared__ float dled[4][32];                      //     512 B

    f32x4 acc[4][5];   // [i-strip][d-tile] PV accumulators
#pragma unroll
    for (int s = 0; s < 4; ++s)
#pragma unroll
        for (int t = 0; t < 5; ++t) acc[s][t] = f32x4{0.f, 0.f, 0.f, 0.f};
    float dsum[2][4] = {{0.f, 0.f, 0.f, 0.f}, {0.f, 0.f, 0.f, 0.f}};

    // A fragments for this wave's i-half: rows i = ib + wi*32 + si*16 + lr
    short8 afr[2][7];
#pragma unroll
    for (int si = 0; si < 2; ++si) {
        const ushort* Ar = A + (size_t)(ib + wi * 32 + si * 16 + lr) * 224 + lg * 8;
#pragma unroll
        for (int k = 0; k < 7; ++k) afr[si][k] = *(const short8*)(Ar + k * 32);
    }

    // B source this wave stages: row j = jo + jb + w*16 + lr, col q*32 + lg*8
    const ushort* Brow = B + (size_t)(jo + w * 16 + lr) * 224 + lg * 8;
    const ushort* Sbase = St + (size_t)(w * 80 + lr) * 8192 + jo + lg * 8;

    // prologue: stage B(0) -> Bl[0]
#pragma unroll
    for (int q = 0; q < 7; ++q)
        gload_lds16(Brow + q * 32, &Bl[0][(w * 7 + q) * 512]);
    __syncthreads();   // drains vmcnt -> Bl[0] ready

    int cur = 0;
    for (int jb = 0; jb < 4096; jb += 64, cur ^= 1) {
        // stage B(jb+64) -> Bl[cur^1]; drains at THIS iter's barrier
        if (jb + 64 < 4096) {
#pragma unroll
            for (int q = 0; q < 7; ++q)
                gload_lds16(Brow + (size_t)(jb + 64) * 224 + q * 32,
                            &Bl[cur ^ 1][(w * 7 + q) * 512]);
        }
        // issue St h0 loads early (consumed in PV h0 after the barrier)
        short8 st0[5];
#pragma unroll
        for (int t = 0; t < 5; ++t)
            st0[t] = *(const short8*)(Sbase + (size_t)t * 16 * 8192 + jb);

        // ---- E: wave (wi,wj) computes E[32 i x 32 j] from Bl[cur] ----
        f32x4 e[2][2];
#pragma unroll
        for (int si = 0; si < 2; ++si)
#pragma unroll
            for (int jt = 0; jt < 2; ++jt) e[si][jt] = f32x4{0.f, 0.f, 0.f, 0.f};
#pragma unroll
        for (int kk = 0; kk < 7; ++kk) {
            short8 b0 = *(const short8*)&Bl[cur][((2 * wj + 0) * 7 + kk) * 512 + lane * 8];
            short8 b1 = *(const short8*)&Bl[cur][((2 * wj + 1) * 7 + kk) * 512 + lane * 8];
            e[0][0] = __builtin_amdgcn_mfma_f32_16x16x32_bf16(afr[0][kk], b0, e[0][0], 0, 0, 0);
            e[0][1] = __builtin_amdgcn_mfma_f32_16x16x32_bf16(afr[0][kk], b1, e[0][1], 0, 0, 0);
            e[1][0] = __builtin_amdgcn_mfma_f32_16x16x32_bf16(afr[1][kk], b0, e[1][0], 0, 0, 0);
            e[1][1] = __builtin_amdgcn_mfma_f32_16x16x32_bf16(afr[1][kk], b1, e[1][1], 0, 0, 0);
        }

        // issue St h1 loads (consumed in PV h1; covered by exp+barrier+PVh0)
        short8 st1[5];
#pragma unroll
        for (int t = 0; t < 5; ++t)
            st1[t] = *(const short8*)(Sbase + (size_t)t * 16 * 8192 + jb + 32);

        // exp (no max-sub: args ~2..5); per-lane partial denom; P -> Pl[cur]
#pragma unroll
        for (int si = 0; si < 2; ++si)
#pragma unroll
            for (int jt = 0; jt < 2; ++jt)
#pragma unroll
                for (int r = 0; r < 4; ++r) {
                    float x = __expf(e[si][jt][r]);
                    dsum[si][r] += x;
                    Pl[cur][wi * 32 + si * 16 + lg * 4 + r][wj * 32 + jt * 16 + lr] = f2bf(x);
                }
        __syncthreads();   // single barrier: Pl[cur] visible, Bl[cur^1] drained

        // ---- PV: wave w, d-quarter [80w,+80), j-window [jb, jb+64) ----
        {
            short8 pf[4];
#pragma unroll
            for (int s = 0; s < 4; ++s)
                pf[s] = *(const short8*)&Pl[cur][s * 16 + lr][lg * 8];
#pragma unroll
            for (int s = 0; s < 4; ++s)
#pragma unroll
                for (int t = 0; t < 5; ++t)
                    acc[s][t] = __builtin_amdgcn_mfma_f32_16x16x32_bf16(pf[s], st0[t], acc[s][t], 0, 0, 0);
#pragma unroll
            for (int s = 0; s < 4; ++s)
                pf[s] = *(const short8*)&Pl[cur][s * 16 + lr][32 + lg * 8];
#pragma unroll
            for (int s = 0; s < 4; ++s)
#pragma unroll
                for (int t = 0; t < 5; ++t)
                    acc[s][t] = __builtin_amdgcn_mfma_f32_16x16x32_bf16(pf[s], st1[t], acc[s][t], 0, 0, 0);
        }
        // no second barrier: next iter writes Pl[cur^1] / stages Bl[cur]
    }

    // denominator: wave holds partials for i-half wi over its 32 j-cols;
    // reduce over 16 lr lanes, publish, sum the wj pair.
#pragma unroll
    for (int m = 1; m < 16; m <<= 1)
#pragma unroll
        for (int si = 0; si < 2; ++si)
#pragma unroll
            for (int r = 0; r < 4; ++r)
                dsum[si][r] += __shfl_xor(dsum[si][r], m);
    if (lr == 0) {
#pragma unroll
        for (int si = 0; si < 2; ++si)
#pragma unroll
            for (int r = 0; r < 4; ++r)
                dled[w][si * 16 + lg * 4 + r] = dsum[si][r];
    }
    __syncthreads();

    // Dpart[jh][dir*8192 + ib + i]: i = wi2*32 + idx; sum the wj pair
    if (tid < 64) {
        int wi2 = tid >> 5, idx = tid & 31;
        Dpart[(size_t)jh * 16384 + dir * 8192 + ib + tid] =
            dled[wi2 * 2][idx] + dled[wi2 * 2 + 1][idx];
    }

    // raw partials: Pacc[jh][dir*8192 + i][d]
    float* Pb = Pacc + ((size_t)jh * 16384 + dir * 8192 + ib) * 320;
#pragma unroll
    for (int t = 0; t < 5; ++t) {
        int d = w * 80 + t * 16 + lr;
#pragma unroll
        for (int s = 0; s < 4; ++s)
#pragma unroll
            for (int r = 0; r < 4; ++r)
                Pb[(size_t)(s * 16 + lg * 4 + r) * 320 + d] = acc[s][t][r];
    }
}

// ---------------------------------------------------------------------------
// combine: beta/alpha = (PaccA + PaccB) / (DA + DB) -> bf16 into Xcat[.,300+]
// ---------------------------------------------------------------------------
__global__ __launch_bounds__(256) void combine_kernel(
    const float* __restrict__ Pacc, const float* __restrict__ Dpart,
    ushort* __restrict__ Xcat)
{
    const int row = blockIdx.x * 8 + (threadIdx.x >> 5);
    const int c0 = threadIdx.x & 31;
    const float inv = 1.f / (Dpart[row] + Dpart[16384 + row]);
    const float* pa = Pacc + (size_t)row * 320;
    const float* pb = Pacc + (size_t)(16384 + row) * 320;
    ushort* xc = Xcat + (size_t)row * 608 + 300;
    for (int d = c0; d < 300; d += 32)
        xc[d] = f2bf((pa[d] + pb[d]) * inv);
}

// ---------------------------------------------------------------------------
// hsum[c] = sum_r v[r][c%200] over the half selected by c/200. c in [0,400).
// ---------------------------------------------------------------------------
__global__ __launch_bounds__(256) void colsum_kernel(
    const float* __restrict__ v, float* __restrict__ hsum)
{
    const int c = blockIdx.x;
    const float* V = v + (c < 200 ? 0 : (size_t)8192 * 200);
    const int col = c % 200;
    float s = 0.f;
    for (int r = threadIdx.x; r < 8192; r += 256)
        s += V[(size_t)r * 200 + col];
    __shared__ float red[256];
    red[threadIdx.x] = s;
    __syncthreads();
    for (int off = 128; off > 0; off >>= 1) {
        if (threadIdx.x < off) red[threadIdx.x] += red[threadIdx.x + off];
        __syncthreads();
    }
    if (threadIdx.x == 0) hsum[c] = red[0];
}

__global__ __launch_bounds__(256) void head_kernel(
    const float* __restrict__ hsum,
    const float* __restrict__ Hw1, const float* __restrict__ Hb1,
    const float* __restrict__ Hw2, const float* __restrict__ Hb2,
    float* __restrict__ out)
{
    __shared__ float hx[400];
    __shared__ float hr[200];
    __shared__ float lg[3];
    const int t = threadIdx.x;
    for (int i = t; i < 400; i += 256) hx[i] = hsum[i];
    __syncthreads();
    if (t < 200) {
        float a = Hb1[t];
        for (int k = 0; k < 400; ++k) a = fmaf(hx[k], Hw1[t * 400 + k], a);
        hr[t] = fmaxf(a, 0.f);
    }
    __syncthreads();
    if (t < 3) {
        float a = Hb2[t];
        for (int k = 0; k < 200; ++k) a = fmaf(hr[k], Hw2[t * 200 + k], a);
        lg[t] = a;
    }
    __syncthreads();
    if (t == 0) {
        float m = fmaxf(lg[0], fmaxf(lg[1], lg[2]));
        float e0 = __expf(lg[0] - m);
        float e1 = __expf(lg[1] - m);
        float e2 = __expf(lg[2] - m);
        float s = e0 + e1 + e2;
        out[0] = e0 / s;
        out[1] = e1 / s;
        out[2] = e2 / s;
    }
}

extern "C" void kernel_launch(void* const* d_in, const int* in_sizes, int n_in,
                              void* d_out, int out_size, void* d_ws, size_t ws_size,
                              hipStream_t stream)
{
    const float* sen1 = (const float*)d_in[0];
    const float* sen2 = (const float*)d_in[1];
    const float* F_w1 = (const float*)d_in[2];
    const float* F_b1 = (const float*)d_in[3];
    const float* F_w2 = (const float*)d_in[4];
    const float* F_b2 = (const float*)d_in[5];
    const float* G_w1 = (const float*)d_in[6];
    const float* G_b1 = (const float*)d_in[7];
    const float* G_w2 = (const float*)d_in[8];
    const float* G_b2 = (const float*)d_in[9];
    const float* H_w1 = (const float*)d_in[10];
    const float* H_b1 = (const float*)d_in[11];
    const float* H_w2 = (const float*)d_in[12];
    const float* H_b2 = (const float*)d_in[13];
    float* out = (float*)d_out;

    const int L = 8192;
    char* p = (char*)d_ws;
    ushort* St1  = (ushort*)p; p += (size_t)320 * L * 2;       // 5.24 MB
    ushort* St2  = (ushort*)p; p += (size_t)320 * L * 2;       // 5.24 MB
    ushort* FaFb = (ushort*)p; p += (size_t)2 * L * 224 * 2;   // 7.34 MB
    ushort* Xcat = (ushort*)p; p += (size_t)2 * L * 608 * 2;   // 19.92 MB
    ushort* WbF1 = (ushort*)p; p += (size_t)224 * 320 * 2;
    ushort* WbF2 = (ushort*)p; p += (size_t)224 * 224 * 2;
    ushort* WbG1 = (ushort*)p; p += (size_t)224 * 608 * 2;
    ushort* WbG2 = (ushort*)p; p += (size_t)224 * 224 * 2;
    float*  bpF1 = (float*)p;  p += 224 * 4;
    float*  bpF2 = (float*)p;  p += 224 * 4;
    float*  bpG1 = (float*)p;  p += 224 * 4;
    float*  bpG2 = (float*)p;  p += 224 * 4;
    float*  hsum = (float*)p;  p += 400 * 4;
    // union region U: Senb (10.5 MB, pre-attend) / Pacc+Dpart (42.1 MB,
    // attend+combine) / v (26.2 MB, post-combine)
    ushort* Senb  = (ushort*)p;
    float*  Pacc  = (float*)p;
    float*  Dpart = (float*)(p + (size_t)2 * 16384 * 320 * 4);
    float*  v     = (float*)p;

    dim3 blk256(256);

    hipLaunchKernelGGL(convert_inputs_kernel, dim3(2 * L / 8), blk256, 0, stream,
                       sen1, sen2, Senb, Xcat);
    hipLaunchKernelGGL(transpose_bf16_kernel, dim3(L / 64, 5, 2), blk256, 0, stream,
                       sen1, sen2, St1, St2);
    hipLaunchKernelGGL(convert_weights_kernel, dim3(4 * 224), blk256, 0, stream,
                       F_w1, F_b1, F_w2, F_b2, G_w1, G_b1, G_w2, G_b2,
                       WbF1, bpF1, WbF2, bpF2, WbG1, bpG1, WbG2, bpG2);

    // F MLP fused (both sentences, M = 16384) -> FaFb bf16
    hipLaunchKernelGGL(mlp2_kernel, dim3(2 * L / 16), dim3(64), 0, stream,
                       Senb, 320, WbF1, bpF1, WbF2, bpF2, FaFb, (float*)nullptr);

    // flash attend, j-split partials
    hipLaunchKernelGGL(attend_mfma_kernel, dim3(512), blk256, 0, stream,
                       FaFb, St1, St2, Pacc, Dpart);
    // combine -> Xcat cols 300..599
    hipLaunchKernelGGL(combine_kernel, dim3(16384 / 8), blk256, 0, stream,
                       Pacc, Dpart, Xcat);

    // G MLP fused -> v f32
    hipLaunchKernelGGL(mlp2_kernel, dim3(2 * L / 16), dim3(64), 0, stream,
                       Xcat, 608, WbG1, bpG1, WbG2, bpG2, (ushort*)nullptr, v);

    hipLaunchKernelGGL(colsum_kernel, dim3(400), blk256, 0, stream, v, hsum);
    hipLaunchKernelGGL(head_kernel, dim3(1), blk256, 0, stream,
                       hsum, H_w1, H_b1, H_w2, H_b2, out);
}

// Round 11
// 303.890 us; speedup vs baseline: 1.1739x; 1.1739x over previous
//
#include <hip/hip_runtime.h>

typedef __attribute__((ext_vector_type(8))) short short8;   // 8 bf16
typedef __attribute__((ext_vector_type(4))) float f32x4;

__device__ inline ushort f2bf(float f) {
    union { float f; unsigned u; } v{f};
    unsigned r = v.u + 0x7FFF + ((v.u >> 16) & 1);
    return (ushort)(r >> 16);
}

// CK-style addrspace casts (low 32 bits of a flat LDS address == LDS offset).
__device__ inline void gload_lds16(const void* g, void* l) {
    __builtin_amdgcn_global_load_lds(
        (const __attribute__((address_space(1))) unsigned int*)(uintptr_t)g,
        (__attribute__((address_space(3))) unsigned int*)(uintptr_t)l,
        16, 0, 0);
}

// ---------------------------------------------------------------------------
// sen1/sen2 f32 [8192][300] -> Senb bf16 [16384][320] (zero-padded) and
// Xcat bf16 [16384][608]: cols 0..299 = sen, cols 600..607 = 0.
// ---------------------------------------------------------------------------
__global__ __launch_bounds__(256) void convert_inputs_kernel(
    const float* __restrict__ sen1, const float* __restrict__ sen2,
    ushort* __restrict__ Senb, ushort* __restrict__ Xcat)
{
    const int row = blockIdx.x * 8 + (threadIdx.x >> 5);
    const int c0 = threadIdx.x & 31;
    const float* src = (row < 8192) ? (sen1 + (size_t)row * 300)
                                    : (sen2 + (size_t)(row - 8192) * 300);
    ushort* sb = Senb + (size_t)row * 320;
    ushort* xc = Xcat + (size_t)row * 608;
    for (int c = c0; c < 320; c += 32) {
        ushort v = (c < 300) ? f2bf(src[c]) : (ushort)0;
        sb[c] = v;
        if (c < 300) xc[c] = v;
    }
    if (c0 < 8) xc[600 + c0] = 0;
}

// ---------------------------------------------------------------------------
// W [N][K] f32 -> Wb [224][KP] bf16 zero-padded; bias -> biasp [224] f32.
// ---------------------------------------------------------------------------
__global__ __launch_bounds__(256) void convert_weights_kernel(
    const float* __restrict__ W0, const float* __restrict__ b0,
    const float* __restrict__ W1, const float* __restrict__ b1,
    const float* __restrict__ W2, const float* __restrict__ b2,
    const float* __restrict__ W3, const float* __restrict__ b3,
    ushort* __restrict__ Wb0, float* __restrict__ bp0,
    ushort* __restrict__ Wb1, float* __restrict__ bp1,
    ushort* __restrict__ Wb2, float* __restrict__ bp2,
    ushort* __restrict__ Wb3, float* __restrict__ bp3)
{
    const int id = blockIdx.x;
    const int mat = id / 224, n = id % 224;
    const float* W; const float* b; ushort* Wb; float* bp; int N, K, KP;
    if (mat == 0)      { W = W0; b = b0; Wb = Wb0; bp = bp0; N = 200; K = 300; KP = 320; }
    else if (mat == 1) { W = W1; b = b1; Wb = Wb1; bp = bp1; N = 200; K = 200; KP = 224; }
    else if (mat == 2) { W = W2; b = b2; Wb = Wb2; bp = bp2; N = 200; K = 600; KP = 608; }
    else               { W = W3; b = b3; Wb = Wb3; bp = bp3; N = 200; K = 200; KP = 224; }
    for (int k = threadIdx.x; k < KP; k += 256)
        Wb[(size_t)n * KP + k] = (n < N && k < K) ? f2bf(W[(size_t)n * K + k]) : (ushort)0;
    if (threadIdx.x == 0) bp[n] = (n < N) ? b[n] : 0.f;
}

// ---------------------------------------------------------------------------
// sen f32 [8192][300] -> St bf16 [320][8192] transposed (pad rows zero).
// ---------------------------------------------------------------------------
__global__ __launch_bounds__(256) void transpose_bf16_kernel(
    const float* __restrict__ s1, const float* __restrict__ s2,
    ushort* __restrict__ St1, ushort* __restrict__ St2)
{
    const float* X = blockIdx.z ? s2 : s1;
    ushort* Xt = blockIdx.z ? St2 : St1;
    __shared__ float t[64][65];
    const int r0 = blockIdx.x * 64, c0 = blockIdx.y * 64;
    const int tc = threadIdx.x & 63, tr = threadIdx.x >> 6;
    for (int rr = tr; rr < 64; rr += 4) {
        int c = c0 + tc;
        t[rr][tc] = (c < 300) ? X[(size_t)(r0 + rr) * 300 + c] : 0.f;
    }
    __syncthreads();
    for (int rr = tr; rr < 64; rr += 4) {
        int oc = c0 + rr;
        if (oc < 320)
            Xt[(size_t)oc * 8192 + r0 + tc] = f2bf(t[tc][rr]);
    }
}

// ---------------------------------------------------------------------------
// Fused 2-layer MLP: Y = relu(relu(X@W1^T+b1)@W2^T+b2).
// X bf16 [M][KP1]; W1 [224][KP1]; W2 [224][224]; one wave, 16 rows/block.
// ---------------------------------------------------------------------------
__global__ __launch_bounds__(64) void mlp2_kernel(
    const ushort* __restrict__ X, int KP1,
    const ushort* __restrict__ W1, const float* __restrict__ b1,
    const ushort* __restrict__ W2, const float* __restrict__ b2,
    ushort* __restrict__ Ybf, float* __restrict__ Yf)
{
    const int r0 = blockIdx.x * 16;
    const int lane = threadIdx.x;
    const int lr = lane & 15, lg = lane >> 4;

    __shared__ __align__(16) ushort Y1[16][232];

    f32x4 a1[14];
#pragma unroll
    for (int t = 0; t < 14; ++t) a1[t] = f32x4{0.f, 0.f, 0.f, 0.f};

    const ushort* Xrow = X + (size_t)(r0 + lr) * KP1 + lg * 8;
    const ushort* W1r  = W1 + (size_t)lr * KP1 + lg * 8;
    for (int k0 = 0; k0 < KP1; k0 += 32) {
        short8 a = *(const short8*)(Xrow + k0);
#pragma unroll
        for (int t = 0; t < 14; ++t) {
            short8 bfr = *(const short8*)(W1r + (size_t)t * 16 * KP1 + k0);
            a1[t] = __builtin_amdgcn_mfma_f32_16x16x32_bf16(a, bfr, a1[t], 0, 0, 0);
        }
    }
#pragma unroll
    for (int t = 0; t < 14; ++t) {
        int col = t * 16 + lr;
        float bv = b1[col];
#pragma unroll
        for (int rr = 0; rr < 4; ++rr)
            Y1[lg * 4 + rr][col] = f2bf(fmaxf(a1[t][rr] + bv, 0.f));
    }
    __syncthreads();

    f32x4 a2[14];
#pragma unroll
    for (int t = 0; t < 14; ++t) a2[t] = f32x4{0.f, 0.f, 0.f, 0.f};
    const ushort* W2r = W2 + (size_t)lr * 224 + lg * 8;
    for (int k0 = 0; k0 < 224; k0 += 32) {
        short8 a = *(const short8*)&Y1[lr][lg * 8 + k0];
#pragma unroll
        for (int t = 0; t < 14; ++t) {
            short8 bfr = *(const short8*)(W2r + (size_t)t * 16 * 224 + k0);
            a2[t] = __builtin_amdgcn_mfma_f32_16x16x32_bf16(a, bfr, a2[t], 0, 0, 0);
        }
    }
#pragma unroll
    for (int t = 0; t < 14; ++t) {
        int col = t * 16 + lr;
        float bv = b2[col];
#pragma unroll
        for (int rr = 0; rr < 4; ++rr) {
            int row = r0 + lg * 4 + rr;
            float v = fmaxf(a2[t][rr] + bv, 0.f);
            if (Ybf) Ybf[(size_t)row * 224 + col] = f2bf(v);
            else if (col < 200) Yf[(size_t)row * 200 + col] = v;
        }
    }
}

// ---------------------------------------------------------------------------
// Flash attend, j-split, BIG i-tile: 128 Q-rows x 4096 j per block,
// 512 threads = 8 waves, grid 256 = 1 block/CU (2 waves/SIMD).
// Rationale (R10 post-mortem): all i=64 variants pinned at ~9.8 TB/s of
// L2-served traffic; halving per-output B/St bytes is the lever.
//   E phase: wave (wi=w>>1, wj=w&1) computes E[32 i x 32 j].
//   PV phase: wave (dq=w&3, ih=w>>2) computes O[64 i x 80 d].
// B tile (64j x 224k) staged once per iter into Bl (frag-layout, linear,
// conflict-free). St tile (320d x 64j) staged once per iter into Sl
// (128-B rows, slot-XOR swizzle sl^(row&7), pre-swizzled gload_lds sources)
// -> removes the (dq,ih) St duplication. Both double-buffered; 2 barriers.
// ---------------------------------------------------------------------------
__global__ __launch_bounds__(512, 2) void attend_mfma_kernel(
    const ushort* __restrict__ FaFb, const ushort* __restrict__ St1,
    const ushort* __restrict__ St2, float* __restrict__ Pacc,
    float* __restrict__ Dpart)
{
    const int b = blockIdx.x;
    const int it  = b & 63;
    const int jh  = (b >> 6) & 1;
    const int dir = b >> 7;
    const ushort* A  = FaFb + (dir ? (size_t)8192 * 224 : 0);
    const ushort* B  = FaFb + (dir ? 0 : (size_t)8192 * 224);
    const ushort* St = dir ? St1 : St2;
    const int ib = it * 128;
    const int jo = jh * 4096;

    const int tid = threadIdx.x;
    const int w = tid >> 6;                 // 0..7
    const int wi = w >> 1, wj = w & 1;      // E roles
    const int dq = w & 3,  ih = w >> 2;     // PV roles
    const int lane = tid & 63;
    const int lr = lane & 15, lg = lane >> 4;

    __shared__ __align__(16) ushort Bl[2][28 * 512];   // 57,344 B
    __shared__ __align__(16) ushort Sl[2][40 * 512];   // 81,920 B
    __shared__ __align__(16) ushort Pl[128][76];       // 19,456 B
    __shared__ float dled[8][32];                      //  1,024 B  (sum 159,744)

    f32x4 acc[4][5];
#pragma unroll
    for (int s = 0; s < 4; ++s)
#pragma unroll
        for (int t = 0; t < 5; ++t) acc[s][t] = f32x4{0.f, 0.f, 0.f, 0.f};
    float dsum[2][4] = {{0.f, 0.f, 0.f, 0.f}, {0.f, 0.f, 0.f, 0.f}};

    // A fragments: rows i = ib + wi*32 + si*16 + lr
    short8 afr[2][7];
#pragma unroll
    for (int si = 0; si < 2; ++si) {
        const ushort* Ar = A + (size_t)(ib + wi * 32 + si * 16 + lr) * 224 + lg * 8;
#pragma unroll
        for (int k = 0; k < 7; ++k) afr[si][k] = *(const short8*)(Ar + k * 32);
    }

    // ---- staging descriptors (computed once) ----
    // B: 28 chunks of 1024 B, frag-layout: chunk p holds rows (p/7)*16+lr,
    // k-cols (p%7)*32+lg*8. waves 0-3: 4 chunks; waves 4-7: 3 chunks.
    const int nB = (w < 4) ? 4 : 3;
    const int pB = (w < 4) ? (w * 4) : (16 + (w - 4) * 3);
    int boff[4];
#pragma unroll
    for (int q = 0; q < 4; ++q) {
        int p = pB + q;
        boff[q] = ((p / 7) * 16 + lr) * 448 + ((p % 7) * 32 + lg * 8) * 2;
    }
    const char* Bb = (const char*)B + (size_t)jo * 448;

    // St: 40 chunks of 1024 B; Sl row = d (0..319), 8 slots of 16B, physical
    // slot = logical ^ (row&7). chunk p: lane l -> row p*8 + (l>>3), phys
    // slot l&7, logical slot (l&7)^(row&7).
    int soff[5];
#pragma unroll
    for (int q = 0; q < 5; ++q) {
        int p = w * 5 + q;
        int srow = p * 8 + (lane >> 3);
        int sl = (lane & 7) ^ (srow & 7);
        soff[q] = srow * 16384 + sl * 16;
    }
    const char* Sb = (const char*)St + (size_t)jo * 2;

    // PV St-read row constants: row = dq*80 + t*16 + lr
    int prow[5], prow7[5];
#pragma unroll
    for (int t = 0; t < 5; ++t) {
        prow[t] = (dq * 80 + t * 16 + lr) * 128;
        prow7[t] = (dq * 80 + t * 16 + lr) & 7;
    }

    // ---- prologue: stage B(0), St(0) into buffer 0 ----
#pragma unroll
    for (int q = 0; q < 4; ++q)
        if (q < nB) gload_lds16(Bb + boff[q], &Bl[0][(pB + q) * 512]);
#pragma unroll
    for (int q = 0; q < 5; ++q)
        gload_lds16(Sb + soff[q], &Sl[0][(w * 5 + q) * 512]);
    __syncthreads();   // drains vmcnt -> buffers ready

    int buf = 0;
    for (int jb = 0; jb < 4096; jb += 64, buf ^= 1) {
        // ---- E: wave (wi,wj) computes E[32 i x 32 j] from Bl[buf] ----
        f32x4 e[2][2];
#pragma unroll
        for (int si = 0; si < 2; ++si)
#pragma unroll
            for (int jt = 0; jt < 2; ++jt) e[si][jt] = f32x4{0.f, 0.f, 0.f, 0.f};
#pragma unroll
        for (int kk = 0; kk < 7; ++kk) {
            short8 b0 = *(const short8*)&Bl[buf][((2 * wj + 0) * 7 + kk) * 512 + lane * 8];
            short8 b1 = *(const short8*)&Bl[buf][((2 * wj + 1) * 7 + kk) * 512 + lane * 8];
            e[0][0] = __builtin_amdgcn_mfma_f32_16x16x32_bf16(afr[0][kk], b0, e[0][0], 0, 0, 0);
            e[0][1] = __builtin_amdgcn_mfma_f32_16x16x32_bf16(afr[0][kk], b1, e[0][1], 0, 0, 0);
            e[1][0] = __builtin_amdgcn_mfma_f32_16x16x32_bf16(afr[1][kk], b0, e[1][0], 0, 0, 0);
            e[1][1] = __builtin_amdgcn_mfma_f32_16x16x32_bf16(afr[1][kk], b1, e[1][1], 0, 0, 0);
        }

        // exp (no max-sub: args ~2..5); per-lane partial denom; P -> Pl
#pragma unroll
        for (int si = 0; si < 2; ++si)
#pragma unroll
            for (int jt = 0; jt < 2; ++jt)
#pragma unroll
                for (int r = 0; r < 4; ++r) {
                    float x = __expf(e[si][jt][r]);
                    dsum[si][r] += x;
                    Pl[wi * 32 + si * 16 + lg * 4 + r][wj * 32 + jt * 16 + lr] = f2bf(x);
                }
        __syncthreads();   // barrier1: Pl ready; Bl[buf] consumed; prev PV done

        // stage next tiles into [buf^1]; drained by barrier2 (PV covers)
        if (jb + 64 < 4096) {
            const char* Bn = Bb + (size_t)(jb + 64) * 448;
            const char* Sn = Sb + (size_t)(jb + 64) * 2;
#pragma unroll
            for (int q = 0; q < 4; ++q)
                if (q < nB) gload_lds16(Bn + boff[q], &Bl[buf ^ 1][(pB + q) * 512]);
#pragma unroll
            for (int q = 0; q < 5; ++q)
                gload_lds16(Sn + soff[q], &Sl[buf ^ 1][(w * 5 + q) * 512]);
        }

        // ---- PV: wave (dq,ih) computes O[64 i x 80 d] over these 64 j ----
#pragma unroll
        for (int h = 0; h < 2; ++h) {
            short8 pf[4];
#pragma unroll
            for (int s = 0; s < 4; ++s)
                pf[s] = *(const short8*)&Pl[ih * 64 + s * 16 + lr][h * 32 + lg * 8];
            short8 st[5];
#pragma unroll
            for (int t = 0; t < 5; ++t) {
                int sl = ((h << 2) | lg) ^ prow7[t];
                st[t] = *(const short8*)((const char*)Sl[buf] + prow[t] + (sl << 4));
            }
#pragma unroll
            for (int s = 0; s < 4; ++s)
#pragma unroll
                for (int t = 0; t < 5; ++t)
                    acc[s][t] = __builtin_amdgcn_mfma_f32_16x16x32_bf16(pf[s], st[t], acc[s][t], 0, 0, 0);
        }
        __syncthreads();   // barrier2: Pl consumed; staging drained
    }

    // denominator: reduce over 16 lr lanes; publish per-wave rows; combine wj.
#pragma unroll
    for (int m = 1; m < 16; m <<= 1)
#pragma unroll
        for (int si = 0; si < 2; ++si)
#pragma unroll
            for (int r = 0; r < 4; ++r)
                dsum[si][r] += __shfl_xor(dsum[si][r], m);
    if (lr == 0) {
#pragma unroll
        for (int si = 0; si < 2; ++si)
#pragma unroll
            for (int r = 0; r < 4; ++r)
                dled[w][si * 16 + lg * 4 + r] = dsum[si][r];
    }
    __syncthreads();

    // Dpart[jh][dir*8192 + ib + i], i in [0,128): sum the wj pair
    if (tid < 128) {
        int wi2 = tid >> 5, idx = tid & 31;
        Dpart[(size_t)jh * 16384 + dir * 8192 + ib + tid] =
            dled[wi2 * 2][idx] + dled[wi2 * 2 + 1][idx];
    }

    // raw partials: Pacc[jh][dir*8192 + i][d]
    float* Pb = Pacc + ((size_t)jh * 16384 + dir * 8192 + ib + ih * 64) * 320;
#pragma unroll
    for (int t = 0; t < 5; ++t) {
        int d = dq * 80 + t * 16 + lr;
#pragma unroll
        for (int s = 0; s < 4; ++s)
#pragma unroll
            for (int r = 0; r < 4; ++r)
                Pb[(size_t)(s * 16 + lg * 4 + r) * 320 + d] = acc[s][t][r];
    }
}

// ---------------------------------------------------------------------------
// combine: beta/alpha = (PaccA + PaccB) / (DA + DB) -> bf16 into Xcat[.,300+]
// ---------------------------------------------------------------------------
__global__ __launch_bounds__(256) void combine_kernel(
    const float* __restrict__ Pacc, const float* __restrict__ Dpart,
    ushort* __restrict__ Xcat)
{
    const int row = blockIdx.x * 8 + (threadIdx.x >> 5);
    const int c0 = threadIdx.x & 31;
    const float inv = 1.f / (Dpart[row] + Dpart[16384 + row]);
    const float* pa = Pacc + (size_t)row * 320;
    const float* pb = Pacc + (size_t)(16384 + row) * 320;
    ushort* xc = Xcat + (size_t)row * 608 + 300;
    for (int d = c0; d < 300; d += 32)
        xc[d] = f2bf((pa[d] + pb[d]) * inv);
}

// ---------------------------------------------------------------------------
// hsum[c] = sum_r v[r][c%200] over the half selected by c/200. c in [0,400).
// ---------------------------------------------------------------------------
__global__ __launch_bounds__(256) void colsum_kernel(
    const float* __restrict__ v, float* __restrict__ hsum)
{
    const int c = blockIdx.x;
    const float* V = v + (c < 200 ? 0 : (size_t)8192 * 200);
    const int col = c % 200;
    float s = 0.f;
    for (int r = threadIdx.x; r < 8192; r += 256)
        s += V[(size_t)r * 200 + col];
    __shared__ float red[256];
    red[threadIdx.x] = s;
    __syncthreads();
    for (int off = 128; off > 0; off >>= 1) {
        if (threadIdx.x < off) red[threadIdx.x] += red[threadIdx.x + off];
        __syncthreads();
    }
    if (threadIdx.x == 0) hsum[c] = red[0];
}

__global__ __launch_bounds__(256) void head_kernel(
    const float* __restrict__ hsum,
    const float* __restrict__ Hw1, const float* __restrict__ Hb1,
    const float* __restrict__ Hw2, const float* __restrict__ Hb2,
    float* __restrict__ out)
{
    __shared__ float hx[400];
    __shared__ float hr[200];
    __shared__ float lg[3];
    const int t = threadIdx.x;
    for (int i = t; i < 400; i += 256) hx[i] = hsum[i];
    __syncthreads();
    if (t < 200) {
        float a = Hb1[t];
        for (int k = 0; k < 400; ++k) a = fmaf(hx[k], Hw1[t * 400 + k], a);
        hr[t] = fmaxf(a, 0.f);
    }
    __syncthreads();
    if (t < 3) {
        float a = Hb2[t];
        for (int k = 0; k < 200; ++k) a = fmaf(hr[k], Hw2[t * 200 + k], a);
        lg[t] = a;
    }
    __syncthreads();
    if (t == 0) {
        float m = fmaxf(lg[0], fmaxf(lg[1], lg[2]));
        float e0 = __expf(lg[0] - m);
        float e1 = __expf(lg[1] - m);
        float e2 = __expf(lg[2] - m);
        float s = e0 + e1 + e2;
        out[0] = e0 / s;
        out[1] = e1 / s;
        out[2] = e2 / s;
    }
}

extern "C" void kernel_launch(void* const* d_in, const int* in_sizes, int n_in,
                              void* d_out, int out_size, void* d_ws, size_t ws_size,
                              hipStream_t stream)
{
    const float* sen1 = (const float*)d_in[0];
    const float* sen2 = (const float*)d_in[1];
    const float* F_w1 = (const float*)d_in[2];
    const float* F_b1 = (const float*)d_in[3];
    const float* F_w2 = (const float*)d_in[4];
    const float* F_b2 = (const float*)d_in[5];
    const float* G_w1 = (const float*)d_in[6];
    const float* G_b1 = (const float*)d_in[7];
    const float* G_w2 = (const float*)d_in[8];
    const float* G_b2 = (const float*)d_in[9];
    const float* H_w1 = (const float*)d_in[10];
    const float* H_b1 = (const float*)d_in[11];
    const float* H_w2 = (const float*)d_in[12];
    const float* H_b2 = (const float*)d_in[13];
    float* out = (float*)d_out;

    const int L = 8192;
    char* p = (char*)d_ws;
    ushort* St1  = (ushort*)p; p += (size_t)320 * L * 2;       // 5.24 MB
    ushort* St2  = (ushort*)p; p += (size_t)320 * L * 2;       // 5.24 MB
    ushort* FaFb = (ushort*)p; p += (size_t)2 * L * 224 * 2;   // 7.34 MB
    ushort* Xcat = (ushort*)p; p += (size_t)2 * L * 608 * 2;   // 19.92 MB
    ushort* WbF1 = (ushort*)p; p += (size_t)224 * 320 * 2;
    ushort* WbF2 = (ushort*)p; p += (size_t)224 * 224 * 2;
    ushort* WbG1 = (ushort*)p; p += (size_t)224 * 608 * 2;
    ushort* WbG2 = (ushort*)p; p += (size_t)224 * 224 * 2;
    float*  bpF1 = (float*)p;  p += 224 * 4;
    float*  bpF2 = (float*)p;  p += 224 * 4;
    float*  bpG1 = (float*)p;  p += 224 * 4;
    float*  bpG2 = (float*)p;  p += 224 * 4;
    float*  hsum = (float*)p;  p += 400 * 4;
    // union region U: Senb (10.5 MB, pre-attend) / Pacc+Dpart (42.1 MB,
    // attend+combine) / v (26.2 MB, post-combine)
    ushort* Senb  = (ushort*)p;
    float*  Pacc  = (float*)p;
    float*  Dpart = (float*)(p + (size_t)2 * 16384 * 320 * 4);
    float*  v     = (float*)p;

    dim3 blk256(256);

    hipLaunchKernelGGL(convert_inputs_kernel, dim3(2 * L / 8), blk256, 0, stream,
                       sen1, sen2, Senb, Xcat);
    hipLaunchKernelGGL(transpose_bf16_kernel, dim3(L / 64, 5, 2), blk256, 0, stream,
                       sen1, sen2, St1, St2);
    hipLaunchKernelGGL(convert_weights_kernel, dim3(4 * 224), blk256, 0, stream,
                       F_w1, F_b1, F_w2, F_b2, G_w1, G_b1, G_w2, G_b2,
                       WbF1, bpF1, WbF2, bpF2, WbG1, bpG1, WbG2, bpG2);

    // F MLP fused (both sentences, M = 16384) -> FaFb bf16
    hipLaunchKernelGGL(mlp2_kernel, dim3(2 * L / 16), dim3(64), 0, stream,
                       Senb, 320, WbF1, bpF1, WbF2, bpF2, FaFb, (float*)nullptr);

    // flash attend, j-split partials (128-row blocks, 512 threads)
    hipLaunchKernelGGL(attend_mfma_kernel, dim3(256), dim3(512), 0, stream,
                       FaFb, St1, St2, Pacc, Dpart);
    // combine -> Xcat cols 300..599
    hipLaunchKernelGGL(combine_kernel, dim3(16384 / 8), blk256, 0, stream,
                       Pacc, Dpart, Xcat);

    // G MLP fused -> v f32
    hipLaunchKernelGGL(mlp2_kernel, dim3(2 * L / 16), dim3(64), 0, stream,
                       Xcat, 608, WbG1, bpG1, WbG2, bpG2, (ushort*)nullptr, v);

    hipLaunchKernelGGL(colsum_kernel, dim3(400), blk256, 0, stream, v, hsum);
    hipLaunchKernelGGL(head_kernel, dim3(1), blk256, 0, stream,
                       hsum, H_w1, H_b1, H_w2, H_b2, out);
}

// Round 12
// 295.076 us; speedup vs baseline: 1.2090x; 1.0299x over previous
//
#include <hip/hip_runtime.h>

typedef __attribute__((ext_vector_type(8))) short short8;   // 8 bf16
typedef __attribute__((ext_vector_type(4))) float f32x4;

__device__ inline ushort f2bf(float f) {
    union { float f; unsigned u; } v{f};
    unsigned r = v.u + 0x7FFF + ((v.u >> 16) & 1);
    return (ushort)(r >> 16);
}
__device__ inline float bf2f(ushort u) {
    union { unsigned u; float f; } v;
    v.u = ((unsigned)u) << 16;
    return v.f;
}

// CK-style addrspace casts (low 32 bits of a flat LDS address == LDS offset).
__device__ inline void gload_lds16(const void* g, void* l) {
    __builtin_amdgcn_global_load_lds(
        (const __attribute__((address_space(1))) unsigned int*)(uintptr_t)g,
        (__attribute__((address_space(3))) unsigned int*)(uintptr_t)l,
        16, 0, 0);
}

// ---------------------------------------------------------------------------
// Merged input conversion: sen (f32 [8192][300], z picks sentence) ->
//   Senb bf16 [16384][320] (row-major, zero-padded)
//   St   bf16 [320][8192]  (transposed, pad rows zero)
// ---------------------------------------------------------------------------
__global__ __launch_bounds__(256) void convert_sen_kernel(
    const float* __restrict__ s1, const float* __restrict__ s2,
    ushort* __restrict__ Senb, ushort* __restrict__ St1, ushort* __restrict__ St2)
{
    const float* X = blockIdx.z ? s2 : s1;
    ushort* Xt = blockIdx.z ? St2 : St1;
    ushort* Sb = Senb + (size_t)blockIdx.z * 8192 * 320;
    __shared__ float t[64][65];
    const int r0 = blockIdx.x * 64, c0 = blockIdx.y * 64;
    const int tc = threadIdx.x & 63, tr = threadIdx.x >> 6;
    for (int rr = tr; rr < 64; rr += 4) {
        int c = c0 + tc;
        float v = (c < 300) ? X[(size_t)(r0 + rr) * 300 + c] : 0.f;
        t[rr][tc] = v;
        if (c < 320) Sb[(size_t)(r0 + rr) * 320 + c] = f2bf(v);
    }
    __syncthreads();
    for (int rr = tr; rr < 64; rr += 4) {
        int oc = c0 + rr;
        if (oc < 320)
            Xt[(size_t)oc * 8192 + r0 + tc] = f2bf(t[tc][rr]);
    }
}

// ---------------------------------------------------------------------------
// Weights -> bf16 padded. F1 [224][320], F2 [224][224], G2 [224][224].
// G1 -> [224][640] split-pad: cols 0..319 = sen half (300 + pad),
//                             cols 320..639 = beta half (300 + pad).
// ---------------------------------------------------------------------------
__global__ __launch_bounds__(256) void convert_weights_kernel(
    const float* __restrict__ W0, const float* __restrict__ b0,
    const float* __restrict__ W1, const float* __restrict__ b1,
    const float* __restrict__ W2, const float* __restrict__ b2,
    const float* __restrict__ W3, const float* __restrict__ b3,
    ushort* __restrict__ Wb0, float* __restrict__ bp0,
    ushort* __restrict__ Wb1, float* __restrict__ bp1,
    ushort* __restrict__ Wb2, float* __restrict__ bp2,
    ushort* __restrict__ Wb3, float* __restrict__ bp3)
{
    const int id = blockIdx.x;
    const int mat = id / 224, n = id % 224;
    if (mat == 2) {   // G1 split layout
        for (int k = threadIdx.x; k < 640; k += 256) {
            float v = 0.f;
            if (n < 200) {
                if (k < 320) { if (k < 300) v = W2[(size_t)n * 600 + k]; }
                else { int cc = k - 320; if (cc < 300) v = W2[(size_t)n * 600 + 300 + cc]; }
            }
            Wb2[(size_t)n * 640 + k] = f2bf(v);
        }
        if (threadIdx.x == 0) bp2[n] = (n < 200) ? b2[n] : 0.f;
        return;
    }
    const float* W; const float* b; ushort* Wb; float* bp; int N, K, KP;
    if (mat == 0)      { W = W0; b = b0; Wb = Wb0; bp = bp0; N = 200; K = 300; KP = 320; }
    else if (mat == 1) { W = W1; b = b1; Wb = Wb1; bp = bp1; N = 200; K = 200; KP = 224; }
    else               { W = W3; b = b3; Wb = Wb3; bp = bp3; N = 200; K = 200; KP = 224; }
    for (int k = threadIdx.x; k < KP; k += 256)
        Wb[(size_t)n * KP + k] = (n < N && k < K) ? f2bf(W[(size_t)n * K + k]) : (ushort)0;
    if (threadIdx.x == 0) bp[n] = (n < N) ? b[n] : 0.f;
}

// ---------------------------------------------------------------------------
// Fused 2-layer MLP (F): Y = relu(relu(X@W1^T+b1)@W2^T+b2) -> bf16 [M][224].
// ---------------------------------------------------------------------------
__global__ __launch_bounds__(64) void mlp2_kernel(
    const ushort* __restrict__ X, int KP1,
    const ushort* __restrict__ W1, const float* __restrict__ b1,
    const ushort* __restrict__ W2, const float* __restrict__ b2,
    ushort* __restrict__ Ybf)
{
    const int r0 = blockIdx.x * 16;
    const int lane = threadIdx.x;
    const int lr = lane & 15, lg = lane >> 4;

    __shared__ __align__(16) ushort Y1[16][232];

    f32x4 a1[14];
#pragma unroll
    for (int t = 0; t < 14; ++t) a1[t] = f32x4{0.f, 0.f, 0.f, 0.f};

    const ushort* Xrow = X + (size_t)(r0 + lr) * KP1 + lg * 8;
    const ushort* W1r  = W1 + (size_t)lr * KP1 + lg * 8;
    for (int k0 = 0; k0 < KP1; k0 += 32) {
        short8 a = *(const short8*)(Xrow + k0);
#pragma unroll
        for (int t = 0; t < 14; ++t) {
            short8 bfr = *(const short8*)(W1r + (size_t)t * 16 * KP1 + k0);
            a1[t] = __builtin_amdgcn_mfma_f32_16x16x32_bf16(a, bfr, a1[t], 0, 0, 0);
        }
    }
#pragma unroll
    for (int t = 0; t < 14; ++t) {
        int col = t * 16 + lr;
        float bv = b1[col];
#pragma unroll
        for (int rr = 0; rr < 4; ++rr)
            Y1[lg * 4 + rr][col] = f2bf(fmaxf(a1[t][rr] + bv, 0.f));
    }
    __syncthreads();

    f32x4 a2[14];
#pragma unroll
    for (int t = 0; t < 14; ++t) a2[t] = f32x4{0.f, 0.f, 0.f, 0.f};
    const ushort* W2r = W2 + (size_t)lr * 224 + lg * 8;
    for (int k0 = 0; k0 < 224; k0 += 32) {
        short8 a = *(const short8*)&Y1[lr][lg * 8 + k0];
#pragma unroll
        for (int t = 0; t < 14; ++t) {
            short8 bfr = *(const short8*)(W2r + (size_t)t * 16 * 224 + k0);
            a2[t] = __builtin_amdgcn_mfma_f32_16x16x32_bf16(a, bfr, a2[t], 0, 0, 0);
        }
    }
#pragma unroll
    for (int t = 0; t < 14; ++t) {
        int col = t * 16 + lr;
        float bv = b2[col];
#pragma unroll
        for (int rr = 0; rr < 4; ++rr) {
            int row = r0 + lg * 4 + rr;
            Ybf[(size_t)row * 224 + col] = f2bf(fmaxf(a2[t][rr] + bv, 0.f));
        }
    }
}

// ---------------------------------------------------------------------------
// G-MLP with FUSED combine: layer-1 input = [senb | (PaccA+PaccB)*inv].
// W1 is the [224][640] split-pad layout. Output v bf16 [16384][200].
// ---------------------------------------------------------------------------
__global__ __launch_bounds__(64) void gmlp2_kernel(
    const ushort* __restrict__ Senb,
    const float* __restrict__ Pacc, const float* __restrict__ Dpart,
    const ushort* __restrict__ W1, const float* __restrict__ b1,
    const ushort* __restrict__ W2, const float* __restrict__ b2,
    ushort* __restrict__ v)
{
    const int r0 = blockIdx.x * 16;
    const int lane = threadIdx.x;
    const int lr = lane & 15, lg = lane >> 4;
    const int row = r0 + lr;

    __shared__ __align__(16) ushort Y1[16][232];

    const float inv = 1.f / (Dpart[row] + Dpart[16384 + row]);
    const float* pa = Pacc + (size_t)row * 320;
    const float* pb = pa + (size_t)16384 * 320;

    f32x4 a1[14];
#pragma unroll
    for (int t = 0; t < 14; ++t) a1[t] = f32x4{0.f, 0.f, 0.f, 0.f};

    const ushort* Xrow = Senb + (size_t)row * 320 + lg * 8;
    const ushort* W1r  = W1 + (size_t)lr * 640 + lg * 8;
    for (int k0 = 0; k0 < 640; k0 += 32) {
        short8 a;
        if (k0 < 320) {
            a = *(const short8*)(Xrow + k0);
        } else {
            int kk = k0 - 320 + lg * 8;
            float4 x0 = *(const float4*)(pa + kk);
            float4 x1 = *(const float4*)(pa + kk + 4);
            float4 y0 = *(const float4*)(pb + kk);
            float4 y1 = *(const float4*)(pb + kk + 4);
            a[0] = (short)f2bf((x0.x + y0.x) * inv);
            a[1] = (short)f2bf((x0.y + y0.y) * inv);
            a[2] = (short)f2bf((x0.z + y0.z) * inv);
            a[3] = (short)f2bf((x0.w + y0.w) * inv);
            a[4] = (short)f2bf((x1.x + y1.x) * inv);
            a[5] = (short)f2bf((x1.y + y1.y) * inv);
            a[6] = (short)f2bf((x1.z + y1.z) * inv);
            a[7] = (short)f2bf((x1.w + y1.w) * inv);
        }
#pragma unroll
        for (int t = 0; t < 14; ++t) {
            short8 bfr = *(const short8*)(W1r + (size_t)t * 16 * 640 + k0);
            a1[t] = __builtin_amdgcn_mfma_f32_16x16x32_bf16(a, bfr, a1[t], 0, 0, 0);
        }
    }
#pragma unroll
    for (int t = 0; t < 14; ++t) {
        int col = t * 16 + lr;
        float bv = b1[col];
#pragma unroll
        for (int rr = 0; rr < 4; ++rr)
            Y1[lg * 4 + rr][col] = f2bf(fmaxf(a1[t][rr] + bv, 0.f));
    }
    __syncthreads();

    f32x4 a2[14];
#pragma unroll
    for (int t = 0; t < 14; ++t) a2[t] = f32x4{0.f, 0.f, 0.f, 0.f};
    const ushort* W2r = W2 + (size_t)lr * 224 + lg * 8;
    for (int k0 = 0; k0 < 224; k0 += 32) {
        short8 a = *(const short8*)&Y1[lr][lg * 8 + k0];
#pragma unroll
        for (int t = 0; t < 14; ++t) {
            short8 bfr = *(const short8*)(W2r + (size_t)t * 16 * 224 + k0);
            a2[t] = __builtin_amdgcn_mfma_f32_16x16x32_bf16(a, bfr, a2[t], 0, 0, 0);
        }
    }
#pragma unroll
    for (int t = 0; t < 14; ++t) {
        int col = t * 16 + lr;
        if (col < 200) {
            float bv = b2[col];
#pragma unroll
            for (int rr = 0; rr < 4; ++rr) {
                int orow = r0 + lg * 4 + rr;
                v[(size_t)orow * 200 + col] = f2bf(fmaxf(a2[t][rr] + bv, 0.f));
            }
        }
    }
}

// ---------------------------------------------------------------------------
// Flash attend, j-split, 128 Q-rows x 4096 j per block, 512 thr = 8 waves,
// grid 256 = 1 block/CU (2 waves/SIMD). R11 structure plus:
//  - SWAPPED E (mfma(b,a)): C col=lr->i, row=lg*4+r->j, so P-writes pack to
//    4 ds_write_b64/wave (was 16 scalar b16) — LDS-op diet (R11: LDS 72% of
//    iter budget). Denominator reduces over lg groups (shfl 16,32).
//  - s_setprio(1) around both MFMA clusters (T5; role-diverse phases).
// ---------------------------------------------------------------------------
__global__ __launch_bounds__(512, 2) void attend_mfma_kernel(
    const ushort* __restrict__ FaFb, const ushort* __restrict__ St1,
    const ushort* __restrict__ St2, float* __restrict__ Pacc,
    float* __restrict__ Dpart)
{
    const int b = blockIdx.x;
    const int it  = b & 63;
    const int jh  = (b >> 6) & 1;
    const int dir = b >> 7;
    const ushort* A  = FaFb + (dir ? (size_t)8192 * 224 : 0);
    const ushort* B  = FaFb + (dir ? 0 : (size_t)8192 * 224);
    const ushort* St = dir ? St1 : St2;
    const int ib = it * 128;
    const int jo = jh * 4096;

    const int tid = threadIdx.x;
    const int w = tid >> 6;                 // 0..7
    const int wi = w >> 1, wj = w & 1;      // E roles
    const int dq = w & 3,  ih = w >> 2;     // PV roles
    const int lane = tid & 63;
    const int lr = lane & 15, lg = lane >> 4;

    __shared__ __align__(16) ushort Bl[2][28 * 512];   // 57,344 B
    __shared__ __align__(16) ushort Sl[2][40 * 512];   // 81,920 B
    __shared__ __align__(16) ushort Pl[128][76];       // 19,456 B
    __shared__ float dled[8][32];                      //  1,024 B

    f32x4 acc[4][5];
#pragma unroll
    for (int s = 0; s < 4; ++s)
#pragma unroll
        for (int t = 0; t < 5; ++t) acc[s][t] = f32x4{0.f, 0.f, 0.f, 0.f};
    float dsum[2] = {0.f, 0.f};

    // A fragments: rows i = ib + wi*32 + si*16 + lr
    short8 afr[2][7];
#pragma unroll
    for (int si = 0; si < 2; ++si) {
        const ushort* Ar = A + (size_t)(ib + wi * 32 + si * 16 + lr) * 224 + lg * 8;
#pragma unroll
        for (int k = 0; k < 7; ++k) afr[si][k] = *(const short8*)(Ar + k * 32);
    }

    // staging descriptors
    const int nB = (w < 4) ? 4 : 3;
    const int pB = (w < 4) ? (w * 4) : (16 + (w - 4) * 3);
    int boff[4];
#pragma unroll
    for (int q = 0; q < 4; ++q) {
        int p = pB + q;
        boff[q] = ((p / 7) * 16 + lr) * 448 + ((p % 7) * 32 + lg * 8) * 2;
    }
    const char* Bb = (const char*)B + (size_t)jo * 448;

    int soff[5];
#pragma unroll
    for (int q = 0; q < 5; ++q) {
        int p = w * 5 + q;
        int srow = p * 8 + (lane >> 3);
        int sl = (lane & 7) ^ (srow & 7);
        soff[q] = srow * 16384 + sl * 16;
    }
    const char* Sb = (const char*)St + (size_t)jo * 2;

    int prow[5], prow7[5];
#pragma unroll
    for (int t = 0; t < 5; ++t) {
        prow[t] = (dq * 80 + t * 16 + lr) * 128;
        prow7[t] = (dq * 80 + t * 16 + lr) & 7;
    }

    // prologue: stage B(0), St(0) into buffer 0
#pragma unroll
    for (int q = 0; q < 4; ++q)
        if (q < nB) gload_lds16(Bb + boff[q], &Bl[0][(pB + q) * 512]);
#pragma unroll
    for (int q = 0; q < 5; ++q)
        gload_lds16(Sb + soff[q], &Sl[0][(w * 5 + q) * 512]);
    __syncthreads();

    int buf = 0;
    for (int jb = 0; jb < 4096; jb += 64, buf ^= 1) {
        // ---- E (swapped): wave (wi,wj) computes E[32 i x 32 j] ----
        f32x4 e[2][2];
#pragma unroll
        for (int si = 0; si < 2; ++si)
#pragma unroll
            for (int jt = 0; jt < 2; ++jt) e[si][jt] = f32x4{0.f, 0.f, 0.f, 0.f};
        __builtin_amdgcn_s_setprio(1);
#pragma unroll
        for (int kk = 0; kk < 7; ++kk) {
            short8 b0 = *(const short8*)&Bl[buf][((2 * wj + 0) * 7 + kk) * 512 + lane * 8];
            short8 b1 = *(const short8*)&Bl[buf][((2 * wj + 1) * 7 + kk) * 512 + lane * 8];
            e[0][0] = __builtin_amdgcn_mfma_f32_16x16x32_bf16(b0, afr[0][kk], e[0][0], 0, 0, 0);
            e[1][0] = __builtin_amdgcn_mfma_f32_16x16x32_bf16(b0, afr[1][kk], e[1][0], 0, 0, 0);
            e[0][1] = __builtin_amdgcn_mfma_f32_16x16x32_bf16(b1, afr[0][kk], e[0][1], 0, 0, 0);
            e[1][1] = __builtin_amdgcn_mfma_f32_16x16x32_bf16(b1, afr[1][kk], e[1][1], 0, 0, 0);
        }
        __builtin_amdgcn_s_setprio(0);

        // exp; packed b64 P-writes: lane lr holds i = ..+lr, j = jt*16+lg*4+r
#pragma unroll
        for (int si = 0; si < 2; ++si) {
#pragma unroll
            for (int jt = 0; jt < 2; ++jt) {
                float x0 = __expf(e[si][jt][0]);
                float x1 = __expf(e[si][jt][1]);
                float x2 = __expf(e[si][jt][2]);
                float x3 = __expf(e[si][jt][3]);
                dsum[si] += (x0 + x1) + (x2 + x3);
                uint2 pk;
                pk.x = (unsigned)f2bf(x0) | ((unsigned)f2bf(x1) << 16);
                pk.y = (unsigned)f2bf(x2) | ((unsigned)f2bf(x3) << 16);
                *(uint2*)&Pl[wi * 32 + si * 16 + lr][wj * 32 + jt * 16 + lg * 4] = pk;
            }
        }
        __syncthreads();   // barrier1: Pl ready; Bl[buf] consumed; prev PV done

        // stage next tiles into [buf^1]; drained by barrier2 (PV covers)
        if (jb + 64 < 4096) {
            const char* Bn = Bb + (size_t)(jb + 64) * 448;
            const char* Sn = Sb + (size_t)(jb + 64) * 2;
#pragma unroll
            for (int q = 0; q < 4; ++q)
                if (q < nB) gload_lds16(Bn + boff[q], &Bl[buf ^ 1][(pB + q) * 512]);
#pragma unroll
            for (int q = 0; q < 5; ++q)
                gload_lds16(Sn + soff[q], &Sl[buf ^ 1][(w * 5 + q) * 512]);
        }

        // ---- PV: wave (dq,ih) computes O[64 i x 80 d] over these 64 j ----
#pragma unroll
        for (int h = 0; h < 2; ++h) {
            short8 pf[4];
#pragma unroll
            for (int s = 0; s < 4; ++s)
                pf[s] = *(const short8*)&Pl[ih * 64 + s * 16 + lr][h * 32 + lg * 8];
            short8 st[5];
#pragma unroll
            for (int t = 0; t < 5; ++t) {
                int sl = ((h << 2) | lg) ^ prow7[t];
                st[t] = *(const short8*)((const char*)Sl[buf] + prow[t] + (sl << 4));
            }
            __builtin_amdgcn_s_setprio(1);
#pragma unroll
            for (int s = 0; s < 4; ++s)
#pragma unroll
                for (int t = 0; t < 5; ++t)
                    acc[s][t] = __builtin_amdgcn_mfma_f32_16x16x32_bf16(pf[s], st[t], acc[s][t], 0, 0, 0);
            __builtin_amdgcn_s_setprio(0);
        }
        __syncthreads();   // barrier2: Pl consumed; staging drained
    }

    // denominator: lane lr holds row-partials; reduce over lg groups.
#pragma unroll
    for (int si = 0; si < 2; ++si) {
        dsum[si] += __shfl_xor(dsum[si], 16);
        dsum[si] += __shfl_xor(dsum[si], 32);
    }
    if (lg == 0) {
#pragma unroll
        for (int si = 0; si < 2; ++si)
            dled[w][si * 16 + lr] = dsum[si];
    }
    __syncthreads();

    // Dpart[jh][dir*8192 + ib + i], i in [0,128): sum the wj pair
    if (tid < 128) {
        int wi2 = tid >> 5, idx = tid & 31;
        Dpart[(size_t)jh * 16384 + dir * 8192 + ib + tid] =
            dled[wi2 * 2][idx] + dled[wi2 * 2 + 1][idx];
    }

    // raw partials: Pacc[jh][dir*8192 + i][d] (d in [0,320); 300.. are zeros)
    float* Pb = Pacc + ((size_t)jh * 16384 + dir * 8192 + ib + ih * 64) * 320;
#pragma unroll
    for (int t = 0; t < 5; ++t) {
        int d = dq * 80 + t * 16 + lr;
#pragma unroll
        for (int s = 0; s < 4; ++s)
#pragma unroll
            for (int r = 0; r < 4; ++r)
                Pb[(size_t)(s * 16 + lg * 4 + r) * 320 + d] = acc[s][t][r];
    }
}

// ---------------------------------------------------------------------------
// hsum[c] = sum_r v[r][c%200] (bf16 v) over the half c/200. c in [0,400).
// ---------------------------------------------------------------------------
__global__ __launch_bounds__(256) void colsum_kernel(
    const ushort* __restrict__ v, float* __restrict__ hsum)
{
    const int c = blockIdx.x;
    const ushort* V = v + (c < 200 ? 0 : (size_t)8192 * 200);
    const int col = c % 200;
    float s = 0.f;
    for (int r = threadIdx.x; r < 8192; r += 256)
        s += bf2f(V[(size_t)r * 200 + col]);
    __shared__ float red[256];
    red[threadIdx.x] = s;
    __syncthreads();
    for (int off = 128; off > 0; off >>= 1) {
        if (threadIdx.x < off) red[threadIdx.x] += red[threadIdx.x + off];
        __syncthreads();
    }
    if (threadIdx.x == 0) hsum[c] = red[0];
}

__global__ __launch_bounds__(256) void head_kernel(
    const float* __restrict__ hsum,
    const float* __restrict__ Hw1, const float* __restrict__ Hb1,
    const float* __restrict__ Hw2, const float* __restrict__ Hb2,
    float* __restrict__ out)
{
    __shared__ float hx[400];
    __shared__ float hr[200];
    __shared__ float lg[3];
    const int t = threadIdx.x;
    for (int i = t; i < 400; i += 256) hx[i] = hsum[i];
    __syncthreads();
    if (t < 200) {
        float a = Hb1[t];
        for (int k = 0; k < 400; ++k) a = fmaf(hx[k], Hw1[t * 400 + k], a);
        hr[t] = fmaxf(a, 0.f);
    }
    __syncthreads();
    if (t < 3) {
        float a = Hb2[t];
        for (int k = 0; k < 200; ++k) a = fmaf(hr[k], Hw2[t * 200 + k], a);
        lg[t] = a;
    }
    __syncthreads();
    if (t == 0) {
        float m = fmaxf(lg[0], fmaxf(lg[1], lg[2]));
        float e0 = __expf(lg[0] - m);
        float e1 = __expf(lg[1] - m);
        float e2 = __expf(lg[2] - m);
        float s = e0 + e1 + e2;
        out[0] = e0 / s;
        out[1] = e1 / s;
        out[2] = e2 / s;
    }
}

extern "C" void kernel_launch(void* const* d_in, const int* in_sizes, int n_in,
                              void* d_out, int out_size, void* d_ws, size_t ws_size,
                              hipStream_t stream)
{
    const float* sen1 = (const float*)d_in[0];
    const float* sen2 = (const float*)d_in[1];
    const float* F_w1 = (const float*)d_in[2];
    const float* F_b1 = (const float*)d_in[3];
    const float* F_w2 = (const float*)d_in[4];
    const float* F_b2 = (const float*)d_in[5];
    const float* G_w1 = (const float*)d_in[6];
    const float* G_b1 = (const float*)d_in[7];
    const float* G_w2 = (const float*)d_in[8];
    const float* G_b2 = (const float*)d_in[9];
    const float* H_w1 = (const float*)d_in[10];
    const float* H_b1 = (const float*)d_in[11];
    const float* H_w2 = (const float*)d_in[12];
    const float* H_b2 = (const float*)d_in[13];
    float* out = (float*)d_out;

    const int L = 8192;
    char* p = (char*)d_ws;
    ushort* St1  = (ushort*)p; p += (size_t)320 * L * 2;       // 5.24 MB
    ushort* St2  = (ushort*)p; p += (size_t)320 * L * 2;       // 5.24 MB
    ushort* Senb = (ushort*)p; p += (size_t)2 * L * 320 * 2;   // 10.49 MB
    ushort* FaFb = (ushort*)p; p += (size_t)2 * L * 224 * 2;   // 7.34 MB
    ushort* vbuf = (ushort*)p; p += (size_t)2 * L * 200 * 2;   // 6.55 MB
    ushort* WbF1 = (ushort*)p; p += (size_t)224 * 320 * 2;
    ushort* WbF2 = (ushort*)p; p += (size_t)224 * 224 * 2;
    ushort* WbG1 = (ushort*)p; p += (size_t)224 * 640 * 2;
    ushort* WbG2 = (ushort*)p; p += (size_t)224 * 224 * 2;
    float*  bpF1 = (float*)p;  p += 224 * 4;
    float*  bpF2 = (float*)p;  p += 224 * 4;
    float*  bpG1 = (float*)p;  p += 224 * 4;
    float*  bpG2 = (float*)p;  p += 224 * 4;
    float*  hsum = (float*)p;  p += 400 * 4;
    float*  Pacc = (float*)p;  p += (size_t)2 * 16384 * 320 * 4;  // 41.94 MB
    float*  Dpart= (float*)p;  p += (size_t)2 * 16384 * 4;        // 131 KB

    dim3 blk256(256);

    // merged input convert + transpose
    hipLaunchKernelGGL(convert_sen_kernel, dim3(L / 64, 5, 2), blk256, 0, stream,
                       sen1, sen2, Senb, St1, St2);
    hipLaunchKernelGGL(convert_weights_kernel, dim3(4 * 224), blk256, 0, stream,
                       F_w1, F_b1, F_w2, F_b2, G_w1, G_b1, G_w2, G_b2,
                       WbF1, bpF1, WbF2, bpF2, WbG1, bpG1, WbG2, bpG2);

    // F MLP fused (both sentences, M = 16384) -> FaFb bf16
    hipLaunchKernelGGL(mlp2_kernel, dim3(2 * L / 16), dim3(64), 0, stream,
                       Senb, 320, WbF1, bpF1, WbF2, bpF2, FaFb);

    // flash attend, j-split partials (128-row blocks, 512 threads)
    hipLaunchKernelGGL(attend_mfma_kernel, dim3(256), dim3(512), 0, stream,
                       FaFb, St1, St2, Pacc, Dpart);

    // G MLP with fused combine -> v bf16
    hipLaunchKernelGGL(gmlp2_kernel, dim3(2 * L / 16), dim3(64), 0, stream,
                       Senb, Pacc, Dpart, WbG1, bpG1, WbG2, bpG2, vbuf);

    hipLaunchKernelGGL(colsum_kernel, dim3(400), blk256, 0, stream, vbuf, hsum);
    hipLaunchKernelGGL(head_kernel, dim3(1), blk256, 0, stream,
                       hsum, H_w1, H_b1, H_w2, H_b2, out);
}

// Round 13
// 276.139 us; speedup vs baseline: 1.2919x; 1.0686x over previous
//
#include <hip/hip_runtime.h>

typedef __attribute__((ext_vector_type(8))) short short8;   // 8 bf16
typedef __attribute__((ext_vector_type(4))) float f32x4;

__device__ inline ushort f2bf(float f) {
    union { float f; unsigned u; } v{f};
    unsigned r = v.u + 0x7FFF + ((v.u >> 16) & 1);
    return (ushort)(r >> 16);
}
__device__ inline float bf2f(ushort u) {
    union { unsigned u; float f; } v;
    v.u = ((unsigned)u) << 16;
    return v.f;
}

// CK-style addrspace casts (low 32 bits of a flat LDS address == LDS offset).
__device__ inline void gload_lds16(const void* g, void* l) {
    __builtin_amdgcn_global_load_lds(
        (const __attribute__((address_space(1))) unsigned int*)(uintptr_t)g,
        (__attribute__((address_space(3))) unsigned int*)(uintptr_t)l,
        16, 0, 0);
}

// ---------------------------------------------------------------------------
// Merged input conversion: sen (f32 [8192][300], z picks sentence) ->
//   Senb bf16 [16384][320] (row-major, zero-padded)
//   St   bf16 [320][8192]  (transposed, pad rows zero)
// ---------------------------------------------------------------------------
__global__ __launch_bounds__(256) void convert_sen_kernel(
    const float* __restrict__ s1, const float* __restrict__ s2,
    ushort* __restrict__ Senb, ushort* __restrict__ St1, ushort* __restrict__ St2)
{
    const float* X = blockIdx.z ? s2 : s1;
    ushort* Xt = blockIdx.z ? St2 : St1;
    ushort* Sb = Senb + (size_t)blockIdx.z * 8192 * 320;
    __shared__ float t[64][65];
    const int r0 = blockIdx.x * 64, c0 = blockIdx.y * 64;
    const int tc = threadIdx.x & 63, tr = threadIdx.x >> 6;
    for (int rr = tr; rr < 64; rr += 4) {
        int c = c0 + tc;
        float v = (c < 300) ? X[(size_t)(r0 + rr) * 300 + c] : 0.f;
        t[rr][tc] = v;
        if (c < 320) Sb[(size_t)(r0 + rr) * 320 + c] = f2bf(v);
    }
    __syncthreads();
    for (int rr = tr; rr < 64; rr += 4) {
        int oc = c0 + rr;
        if (oc < 320)
            Xt[(size_t)oc * 8192 + r0 + tc] = f2bf(t[tc][rr]);
    }
}

// ---------------------------------------------------------------------------
// Weights -> bf16 padded. F1 [224][320], F2 [224][224], G2 [224][224].
// G1 -> [224][640] split-pad: cols 0..319 = sen half, 320..639 = beta half.
// ---------------------------------------------------------------------------
__global__ __launch_bounds__(256) void convert_weights_kernel(
    const float* __restrict__ W0, const float* __restrict__ b0,
    const float* __restrict__ W1, const float* __restrict__ b1,
    const float* __restrict__ W2, const float* __restrict__ b2,
    const float* __restrict__ W3, const float* __restrict__ b3,
    ushort* __restrict__ Wb0, float* __restrict__ bp0,
    ushort* __restrict__ Wb1, float* __restrict__ bp1,
    ushort* __restrict__ Wb2, float* __restrict__ bp2,
    ushort* __restrict__ Wb3, float* __restrict__ bp3)
{
    const int id = blockIdx.x;
    const int mat = id / 224, n = id % 224;
    if (mat == 2) {   // G1 split layout
        for (int k = threadIdx.x; k < 640; k += 256) {
            float v = 0.f;
            if (n < 200) {
                if (k < 320) { if (k < 300) v = W2[(size_t)n * 600 + k]; }
                else { int cc = k - 320; if (cc < 300) v = W2[(size_t)n * 600 + 300 + cc]; }
            }
            Wb2[(size_t)n * 640 + k] = f2bf(v);
        }
        if (threadIdx.x == 0) bp2[n] = (n < 200) ? b2[n] : 0.f;
        return;
    }
    const float* W; const float* b; ushort* Wb; float* bp; int N, K, KP;
    if (mat == 0)      { W = W0; b = b0; Wb = Wb0; bp = bp0; N = 200; K = 300; KP = 320; }
    else if (mat == 1) { W = W1; b = b1; Wb = Wb1; bp = bp1; N = 200; K = 200; KP = 224; }
    else               { W = W3; b = b3; Wb = Wb3; bp = bp3; N = 200; K = 200; KP = 224; }
    for (int k = threadIdx.x; k < KP; k += 256)
        Wb[(size_t)n * KP + k] = (n < N && k < K) ? f2bf(W[(size_t)n * K + k]) : (ushort)0;
    if (threadIdx.x == 0) bp[n] = (n < N) ? b[n] : 0.f;
}

// ---------------------------------------------------------------------------
// Fused 2-layer MLP (F): Y = relu(relu(X@W1^T+b1)@W2^T+b2) -> bf16 [M][224].
// ---------------------------------------------------------------------------
__global__ __launch_bounds__(64) void mlp2_kernel(
    const ushort* __restrict__ X, int KP1,
    const ushort* __restrict__ W1, const float* __restrict__ b1,
    const ushort* __restrict__ W2, const float* __restrict__ b2,
    ushort* __restrict__ Ybf)
{
    const int r0 = blockIdx.x * 16;
    const int lane = threadIdx.x;
    const int lr = lane & 15, lg = lane >> 4;

    __shared__ __align__(16) ushort Y1[16][232];

    f32x4 a1[14];
#pragma unroll
    for (int t = 0; t < 14; ++t) a1[t] = f32x4{0.f, 0.f, 0.f, 0.f};

    const ushort* Xrow = X + (size_t)(r0 + lr) * KP1 + lg * 8;
    const ushort* W1r  = W1 + (size_t)lr * KP1 + lg * 8;
    for (int k0 = 0; k0 < KP1; k0 += 32) {
        short8 a = *(const short8*)(Xrow + k0);
#pragma unroll
        for (int t = 0; t < 14; ++t) {
            short8 bfr = *(const short8*)(W1r + (size_t)t * 16 * KP1 + k0);
            a1[t] = __builtin_amdgcn_mfma_f32_16x16x32_bf16(a, bfr, a1[t], 0, 0, 0);
        }
    }
#pragma unroll
    for (int t = 0; t < 14; ++t) {
        int col = t * 16 + lr;
        float bv = b1[col];
#pragma unroll
        for (int rr = 0; rr < 4; ++rr)
            Y1[lg * 4 + rr][col] = f2bf(fmaxf(a1[t][rr] + bv, 0.f));
    }
    __syncthreads();

    f32x4 a2[14];
#pragma unroll
    for (int t = 0; t < 14; ++t) a2[t] = f32x4{0.f, 0.f, 0.f, 0.f};
    const ushort* W2r = W2 + (size_t)lr * 224 + lg * 8;
    for (int k0 = 0; k0 < 224; k0 += 32) {
        short8 a = *(const short8*)&Y1[lr][lg * 8 + k0];
#pragma unroll
        for (int t = 0; t < 14; ++t) {
            short8 bfr = *(const short8*)(W2r + (size_t)t * 16 * 224 + k0);
            a2[t] = __builtin_amdgcn_mfma_f32_16x16x32_bf16(a, bfr, a2[t], 0, 0, 0);
        }
    }
#pragma unroll
    for (int t = 0; t < 14; ++t) {
        int col = t * 16 + lr;
        float bv = b2[col];
#pragma unroll
        for (int rr = 0; rr < 4; ++rr) {
            int row = r0 + lg * 4 + rr;
            Ybf[(size_t)row * 224 + col] = f2bf(fmaxf(a2[t][rr] + bv, 0.f));
        }
    }
}

// ---------------------------------------------------------------------------
// G-MLP with FUSED combine (input = [senb | (PaccA+PaccB)*inv], Pacc bf16)
// and FUSED column-sum epilogue: block's 16 rows reduced per column via
// shfl_xor over lg groups, one coalesced Part[block][200] f32 row written.
// (Replaces the scatter-read colsum over a [16384][200] buffer.)
// ---------------------------------------------------------------------------
__global__ __launch_bounds__(64) void gmlp2_kernel(
    const ushort* __restrict__ Senb,
    const ushort* __restrict__ Pacc, const float* __restrict__ Dpart,
    const ushort* __restrict__ W1, const float* __restrict__ b1,
    const ushort* __restrict__ W2, const float* __restrict__ b2,
    float* __restrict__ Part)
{
    const int r0 = blockIdx.x * 16;
    const int lane = threadIdx.x;
    const int lr = lane & 15, lg = lane >> 4;
    const int row = r0 + lr;

    __shared__ __align__(16) ushort Y1[16][232];

    const float inv = 1.f / (Dpart[row] + Dpart[16384 + row]);
    const ushort* pa = Pacc + (size_t)row * 320;
    const ushort* pb = pa + (size_t)16384 * 320;

    f32x4 a1[14];
#pragma unroll
    for (int t = 0; t < 14; ++t) a1[t] = f32x4{0.f, 0.f, 0.f, 0.f};

    const ushort* Xrow = Senb + (size_t)row * 320 + lg * 8;
    const ushort* W1r  = W1 + (size_t)lr * 640 + lg * 8;
    for (int k0 = 0; k0 < 640; k0 += 32) {
        short8 a;
        if (k0 < 320) {
            a = *(const short8*)(Xrow + k0);
        } else {
            int kk = k0 - 320 + lg * 8;
            short8 x = *(const short8*)(pa + kk);
            short8 y = *(const short8*)(pb + kk);
#pragma unroll
            for (int m = 0; m < 8; ++m)
                a[m] = (short)f2bf((bf2f((ushort)x[m]) + bf2f((ushort)y[m])) * inv);
        }
#pragma unroll
        for (int t = 0; t < 14; ++t) {
            short8 bfr = *(const short8*)(W1r + (size_t)t * 16 * 640 + k0);
            a1[t] = __builtin_amdgcn_mfma_f32_16x16x32_bf16(a, bfr, a1[t], 0, 0, 0);
        }
    }
#pragma unroll
    for (int t = 0; t < 14; ++t) {
        int col = t * 16 + lr;
        float bv = b1[col];
#pragma unroll
        for (int rr = 0; rr < 4; ++rr)
            Y1[lg * 4 + rr][col] = f2bf(fmaxf(a1[t][rr] + bv, 0.f));
    }
    __syncthreads();

    f32x4 a2[14];
#pragma unroll
    for (int t = 0; t < 14; ++t) a2[t] = f32x4{0.f, 0.f, 0.f, 0.f};
    const ushort* W2r = W2 + (size_t)lr * 224 + lg * 8;
    for (int k0 = 0; k0 < 224; k0 += 32) {
        short8 a = *(const short8*)&Y1[lr][lg * 8 + k0];
#pragma unroll
        for (int t = 0; t < 14; ++t) {
            short8 bfr = *(const short8*)(W2r + (size_t)t * 16 * 224 + k0);
            a2[t] = __builtin_amdgcn_mfma_f32_16x16x32_bf16(a, bfr, a2[t], 0, 0, 0);
        }
    }
    // relu + column partial-sum over the block's 16 rows -> Part[block][col]
#pragma unroll
    for (int t = 0; t < 14; ++t) {
        int col = t * 16 + lr;
        if (col < 200) {
            float bv = b2[col];
            float s = 0.f;
#pragma unroll
            for (int rr = 0; rr < 4; ++rr)
                s += fmaxf(a2[t][rr] + bv, 0.f);
            s += __shfl_xor(s, 16);
            s += __shfl_xor(s, 32);
            if (lg == 0)
                Part[(size_t)blockIdx.x * 200 + col] = s;
        }
    }
}

// ---------------------------------------------------------------------------
// Flash attend, j-split, 128 Q-rows x 4096 j per block, 512 thr = 8 waves,
// grid 256 = 1 block/CU (2 waves/SIMD). Frozen R12 structure; epilogue now
// writes Pacc as bf16 (halves partial-buffer traffic; precision margin huge:
// output softmax saturated, absmax 4e-17 at f32 vs 2e-2 threshold).
// ---------------------------------------------------------------------------
__global__ __launch_bounds__(512, 2) void attend_mfma_kernel(
    const ushort* __restrict__ FaFb, const ushort* __restrict__ St1,
    const ushort* __restrict__ St2, ushort* __restrict__ Pacc,
    float* __restrict__ Dpart)
{
    const int b = blockIdx.x;
    const int it  = b & 63;
    const int jh  = (b >> 6) & 1;
    const int dir = b >> 7;
    const ushort* A  = FaFb + (dir ? (size_t)8192 * 224 : 0);
    const ushort* B  = FaFb + (dir ? 0 : (size_t)8192 * 224);
    const ushort* St = dir ? St1 : St2;
    const int ib = it * 128;
    const int jo = jh * 4096;

    const int tid = threadIdx.x;
    const int w = tid >> 6;                 // 0..7
    const int wi = w >> 1, wj = w & 1;      // E roles
    const int dq = w & 3,  ih = w >> 2;     // PV roles
    const int lane = tid & 63;
    const int lr = lane & 15, lg = lane >> 4;

    __shared__ __align__(16) ushort Bl[2][28 * 512];   // 57,344 B
    __shared__ __align__(16) ushort Sl[2][40 * 512];   // 81,920 B
    __shared__ __align__(16) ushort Pl[128][76];       // 19,456 B
    __shared__ float dled[8][32];                      //  1,024 B

    f32x4 acc[4][5];
#pragma unroll
    for (int s = 0; s < 4; ++s)
#pragma unroll
        for (int t = 0; t < 5; ++t) acc[s][t] = f32x4{0.f, 0.f, 0.f, 0.f};
    float dsum[2] = {0.f, 0.f};

    // A fragments: rows i = ib + wi*32 + si*16 + lr
    short8 afr[2][7];
#pragma unroll
    for (int si = 0; si < 2; ++si) {
        const ushort* Ar = A + (size_t)(ib + wi * 32 + si * 16 + lr) * 224 + lg * 8;
#pragma unroll
        for (int k = 0; k < 7; ++k) afr[si][k] = *(const short8*)(Ar + k * 32);
    }

    // staging descriptors
    const int nB = (w < 4) ? 4 : 3;
    const int pB = (w < 4) ? (w * 4) : (16 + (w - 4) * 3);
    int boff[4];
#pragma unroll
    for (int q = 0; q < 4; ++q) {
        int p = pB + q;
        boff[q] = ((p / 7) * 16 + lr) * 448 + ((p % 7) * 32 + lg * 8) * 2;
    }
    const char* Bb = (const char*)B + (size_t)jo * 448;

    int soff[5];
#pragma unroll
    for (int q = 0; q < 5; ++q) {
        int p = w * 5 + q;
        int srow = p * 8 + (lane >> 3);
        int sl = (lane & 7) ^ (srow & 7);
        soff[q] = srow * 16384 + sl * 16;
    }
    const char* Sb = (const char*)St + (size_t)jo * 2;

    int prow[5], prow7[5];
#pragma unroll
    for (int t = 0; t < 5; ++t) {
        prow[t] = (dq * 80 + t * 16 + lr) * 128;
        prow7[t] = (dq * 80 + t * 16 + lr) & 7;
    }

    // prologue: stage B(0), St(0) into buffer 0
#pragma unroll
    for (int q = 0; q < 4; ++q)
        if (q < nB) gload_lds16(Bb + boff[q], &Bl[0][(pB + q) * 512]);
#pragma unroll
    for (int q = 0; q < 5; ++q)
        gload_lds16(Sb + soff[q], &Sl[0][(w * 5 + q) * 512]);
    __syncthreads();

    int buf = 0;
    for (int jb = 0; jb < 4096; jb += 64, buf ^= 1) {
        // ---- E (swapped): wave (wi,wj) computes E[32 i x 32 j] ----
        f32x4 e[2][2];
#pragma unroll
        for (int si = 0; si < 2; ++si)
#pragma unroll
            for (int jt = 0; jt < 2; ++jt) e[si][jt] = f32x4{0.f, 0.f, 0.f, 0.f};
        __builtin_amdgcn_s_setprio(1);
#pragma unroll
        for (int kk = 0; kk < 7; ++kk) {
            short8 b0 = *(const short8*)&Bl[buf][((2 * wj + 0) * 7 + kk) * 512 + lane * 8];
            short8 b1 = *(const short8*)&Bl[buf][((2 * wj + 1) * 7 + kk) * 512 + lane * 8];
            e[0][0] = __builtin_amdgcn_mfma_f32_16x16x32_bf16(b0, afr[0][kk], e[0][0], 0, 0, 0);
            e[1][0] = __builtin_amdgcn_mfma_f32_16x16x32_bf16(b0, afr[1][kk], e[1][0], 0, 0, 0);
            e[0][1] = __builtin_amdgcn_mfma_f32_16x16x32_bf16(b1, afr[0][kk], e[0][1], 0, 0, 0);
            e[1][1] = __builtin_amdgcn_mfma_f32_16x16x32_bf16(b1, afr[1][kk], e[1][1], 0, 0, 0);
        }
        __builtin_amdgcn_s_setprio(0);

        // exp; packed b64 P-writes: lane lr holds i = ..+lr, j = jt*16+lg*4+r
#pragma unroll
        for (int si = 0; si < 2; ++si) {
#pragma unroll
            for (int jt = 0; jt < 2; ++jt) {
                float x0 = __expf(e[si][jt][0]);
                float x1 = __expf(e[si][jt][1]);
                float x2 = __expf(e[si][jt][2]);
                float x3 = __expf(e[si][jt][3]);
                dsum[si] += (x0 + x1) + (x2 + x3);
                uint2 pk;
                pk.x = (unsigned)f2bf(x0) | ((unsigned)f2bf(x1) << 16);
                pk.y = (unsigned)f2bf(x2) | ((unsigned)f2bf(x3) << 16);
                *(uint2*)&Pl[wi * 32 + si * 16 + lr][wj * 32 + jt * 16 + lg * 4] = pk;
            }
        }
        __syncthreads();   // barrier1: Pl ready; Bl[buf] consumed; prev PV done

        // stage next tiles into [buf^1]; drained by barrier2 (PV covers)
        if (jb + 64 < 4096) {
            const char* Bn = Bb + (size_t)(jb + 64) * 448;
            const char* Sn = Sb + (size_t)(jb + 64) * 2;
#pragma unroll
            for (int q = 0; q < 4; ++q)
                if (q < nB) gload_lds16(Bn + boff[q], &Bl[buf ^ 1][(pB + q) * 512]);
#pragma unroll
            for (int q = 0; q < 5; ++q)
                gload_lds16(Sn + soff[q], &Sl[buf ^ 1][(w * 5 + q) * 512]);
        }

        // ---- PV: wave (dq,ih) computes O[64 i x 80 d] over these 64 j ----
#pragma unroll
        for (int h = 0; h < 2; ++h) {
            short8 pf[4];
#pragma unroll
            for (int s = 0; s < 4; ++s)
                pf[s] = *(const short8*)&Pl[ih * 64 + s * 16 + lr][h * 32 + lg * 8];
            short8 st[5];
#pragma unroll
            for (int t = 0; t < 5; ++t) {
                int sl = ((h << 2) | lg) ^ prow7[t];
                st[t] = *(const short8*)((const char*)Sl[buf] + prow[t] + (sl << 4));
            }
            __builtin_amdgcn_s_setprio(1);
#pragma unroll
            for (int s = 0; s < 4; ++s)
#pragma unroll
                for (int t = 0; t < 5; ++t)
                    acc[s][t] = __builtin_amdgcn_mfma_f32_16x16x32_bf16(pf[s], st[t], acc[s][t], 0, 0, 0);
            __builtin_amdgcn_s_setprio(0);
        }
        __syncthreads();   // barrier2: Pl consumed; staging drained
    }

    // denominator: lane lr holds row-partials; reduce over lg groups.
#pragma unroll
    for (int si = 0; si < 2; ++si) {
        dsum[si] += __shfl_xor(dsum[si], 16);
        dsum[si] += __shfl_xor(dsum[si], 32);
    }
    if (lg == 0) {
#pragma unroll
        for (int si = 0; si < 2; ++si)
            dled[w][si * 16 + lr] = dsum[si];
    }
    __syncthreads();

    // Dpart[jh][dir*8192 + ib + i], i in [0,128): sum the wj pair
    if (tid < 128) {
        int wi2 = tid >> 5, idx = tid & 31;
        Dpart[(size_t)jh * 16384 + dir * 8192 + ib + tid] =
            dled[wi2 * 2][idx] + dled[wi2 * 2 + 1][idx];
    }

    // raw partials (bf16): Pacc[jh][dir*8192 + i][d]
    ushort* Pb = Pacc + ((size_t)jh * 16384 + dir * 8192 + ib + ih * 64) * 320;
#pragma unroll
    for (int t = 0; t < 5; ++t) {
        int d = dq * 80 + t * 16 + lr;
#pragma unroll
        for (int s = 0; s < 4; ++s)
#pragma unroll
            for (int r = 0; r < 4; ++r)
                Pb[(size_t)(s * 16 + lg * 4 + r) * 320 + d] = f2bf(acc[s][t][r]);
    }
}

// ---------------------------------------------------------------------------
// hsum[c] = sum_p Part[half*512 + p][c%200], p in [0,512). c in [0,400).
// Tiny: 0.8 MB total read.
// ---------------------------------------------------------------------------
__global__ __launch_bounds__(256) void colsum_part_kernel(
    const float* __restrict__ Part, float* __restrict__ hsum)
{
    const int c = blockIdx.x;
    const int base = (c < 200) ? 0 : 512;
    const int col = c % 200;
    float s = 0.f;
    for (int p = threadIdx.x; p < 512; p += 256)
        s += Part[(size_t)(base + p) * 200 + col];
    __shared__ float red[256];
    red[threadIdx.x] = s;
    __syncthreads();
    for (int off = 128; off > 0; off >>= 1) {
        if (threadIdx.x < off) red[threadIdx.x] += red[threadIdx.x + off];
        __syncthreads();
    }
    if (threadIdx.x == 0) hsum[c] = red[0];
}

__global__ __launch_bounds__(256) void head_kernel(
    const float* __restrict__ hsum,
    const float* __restrict__ Hw1, const float* __restrict__ Hb1,
    const float* __restrict__ Hw2, const float* __restrict__ Hb2,
    float* __restrict__ out)
{
    __shared__ float hx[400];
    __shared__ float hr[200];
    __shared__ float lg[3];
    const int t = threadIdx.x;
    for (int i = t; i < 400; i += 256) hx[i] = hsum[i];
    __syncthreads();
    if (t < 200) {
        float a = Hb1[t];
        for (int k = 0; k < 400; ++k) a = fmaf(hx[k], Hw1[t * 400 + k], a);
        hr[t] = fmaxf(a, 0.f);
    }
    __syncthreads();
    if (t < 3) {
        float a = Hb2[t];
        for (int k = 0; k < 200; ++k) a = fmaf(hr[k], Hw2[t * 200 + k], a);
        lg[t] = a;
    }
    __syncthreads();
    if (t == 0) {
        float m = fmaxf(lg[0], fmaxf(lg[1], lg[2]));
        float e0 = __expf(lg[0] - m);
        float e1 = __expf(lg[1] - m);
        float e2 = __expf(lg[2] - m);
        float s = e0 + e1 + e2;
        out[0] = e0 / s;
        out[1] = e1 / s;
        out[2] = e2 / s;
    }
}

extern "C" void kernel_launch(void* const* d_in, const int* in_sizes, int n_in,
                              void* d_out, int out_size, void* d_ws, size_t ws_size,
                              hipStream_t stream)
{
    const float* sen1 = (const float*)d_in[0];
    const float* sen2 = (const float*)d_in[1];
    const float* F_w1 = (const float*)d_in[2];
    const float* F_b1 = (const float*)d_in[3];
    const float* F_w2 = (const float*)d_in[4];
    const float* F_b2 = (const float*)d_in[5];
    const float* G_w1 = (const float*)d_in[6];
    const float* G_b1 = (const float*)d_in[7];
    const float* G_w2 = (const float*)d_in[8];
    const float* G_b2 = (const float*)d_in[9];
    const float* H_w1 = (const float*)d_in[10];
    const float* H_b1 = (const float*)d_in[11];
    const float* H_w2 = (const float*)d_in[12];
    const float* H_b2 = (const float*)d_in[13];
    float* out = (float*)d_out;

    const int L = 8192;
    char* p = (char*)d_ws;
    ushort* St1  = (ushort*)p; p += (size_t)320 * L * 2;       // 5.24 MB
    ushort* St2  = (ushort*)p; p += (size_t)320 * L * 2;       // 5.24 MB
    ushort* Senb = (ushort*)p; p += (size_t)2 * L * 320 * 2;   // 10.49 MB
    ushort* FaFb = (ushort*)p; p += (size_t)2 * L * 224 * 2;   // 7.34 MB
    ushort* WbF1 = (ushort*)p; p += (size_t)224 * 320 * 2;
    ushort* WbF2 = (ushort*)p; p += (size_t)224 * 224 * 2;
    ushort* WbG1 = (ushort*)p; p += (size_t)224 * 640 * 2;
    ushort* WbG2 = (ushort*)p; p += (size_t)224 * 224 * 2;
    float*  bpF1 = (float*)p;  p += 224 * 4;
    float*  bpF2 = (float*)p;  p += 224 * 4;
    float*  bpG1 = (float*)p;  p += 224 * 4;
    float*  bpG2 = (float*)p;  p += 224 * 4;
    float*  hsum = (float*)p;  p += 400 * 4;
    ushort* Pacc = (ushort*)p; p += (size_t)2 * 16384 * 320 * 2;  // 20.97 MB
    float*  Dpart= (float*)p;  p += (size_t)2 * 16384 * 4;        // 131 KB
    float*  Part = (float*)p;  p += (size_t)1024 * 200 * 4;       // 0.82 MB

    dim3 blk256(256);

    // merged input convert + transpose
    hipLaunchKernelGGL(convert_sen_kernel, dim3(L / 64, 5, 2), blk256, 0, stream,
                       sen1, sen2, Senb, St1, St2);
    hipLaunchKernelGGL(convert_weights_kernel, dim3(4 * 224), blk256, 0, stream,
                       F_w1, F_b1, F_w2, F_b2, G_w1, G_b1, G_w2, G_b2,
                       WbF1, bpF1, WbF2, bpF2, WbG1, bpG1, WbG2, bpG2);

    // F MLP fused (both sentences, M = 16384) -> FaFb bf16
    hipLaunchKernelGGL(mlp2_kernel, dim3(2 * L / 16), dim3(64), 0, stream,
                       Senb, 320, WbF1, bpF1, WbF2, bpF2, FaFb);

    // flash attend, j-split partials (128-row blocks, 512 threads)
    hipLaunchKernelGGL(attend_mfma_kernel, dim3(256), dim3(512), 0, stream,
                       FaFb, St1, St2, Pacc, Dpart);

    // G MLP with fused combine + fused column partial-sum -> Part
    hipLaunchKernelGGL(gmlp2_kernel, dim3(2 * L / 16), dim3(64), 0, stream,
                       Senb, Pacc, Dpart, WbG1, bpG1, WbG2, bpG2, Part);

    // reduce partials -> hsum[400], then head
    hipLaunchKernelGGL(colsum_part_kernel, dim3(400), blk256, 0, stream, Part, hsum);
    hipLaunchKernelGGL(head_kernel, dim3(1), blk256, 0, stream,
                       hsum, H_w1, H_b1, H_w2, H_b2, out);
}